// Round 1
// baseline (390.932 us; speedup 1.0000x reference)
//
#include <hip/hip_runtime.h>

#define D_MODEL 512
#define NHEAD 8
#define DK 64
#define SEQ 4096
#define BATCH 2

typedef short bf16x8 __attribute__((ext_vector_type(8)));
typedef float f32x4 __attribute__((ext_vector_type(4)));
typedef unsigned short u16;
typedef u16 u16x8 __attribute__((ext_vector_type(8)));
typedef u16 u16x4 __attribute__((ext_vector_type(4)));

__device__ __forceinline__ u16 f2bf(float f) {
  union { float f; unsigned u; } v; v.f = f;
  unsigned r = v.u + 0x7fffu + ((v.u >> 16) & 1u);
  return (u16)(r >> 16);
}

// NT GEMM: C[m][e] = sum_d X[m][d] * W[e][d] + bias[e]; M=8192, N=K=512.
// MODE 0: X fp32, out bf16 -> Qh[b][h][s][dk], scaled by 0.125
// MODE 1: X fp32, out bf16 -> Kh[b][h][s][dk]
// MODE 2: X fp32, out bf16 -> Vt[b][h][dk][s]   (transposed)
// MODE 3: X bf16, out fp32 -> [b][s][e]
template<int MODE>
__global__ __launch_bounds__(256, 2)
void gemm_proj(const void* __restrict__ Xv, const float* __restrict__ W,
               const float* __restrict__ bias, void* __restrict__ Outv)
{
  __shared__ alignas(16) u16 Alds[128][72];
  __shared__ alignas(16) u16 Blds[128][72];
  const int t = threadIdx.x;
  const int bx = blockIdx.x & 63;   // m tile
  const int by = blockIdx.x >> 6;   // n tile
  const int m0 = bx << 7, n0 = by << 7;
  const int lane = t & 63, w = t >> 6;
  const int lr = lane & 15, lg = lane >> 4;
  const int wr = w >> 1, wc = w & 1;

  f32x4 acc[4][4];
  #pragma unroll
  for (int i = 0; i < 4; ++i)
    #pragma unroll
    for (int j = 0; j < 4; ++j) acc[i][j] = (f32x4){0.f, 0.f, 0.f, 0.f};

  for (int k0 = 0; k0 < 512; k0 += 64) {
    // ---- stage A tile [128][64] ----
    if (MODE < 3) {
      const float* X = (const float*)Xv;
      #pragma unroll
      for (int i = 0; i < 8; ++i) {
        int f = (i << 8) + t;
        int row = f >> 4, c4 = (f & 15) << 2;
        float4 x = *(const float4*)(X + (size_t)(m0 + row) * 512 + k0 + c4);
        u16x4 p = { f2bf(x.x), f2bf(x.y), f2bf(x.z), f2bf(x.w) };
        *(u16x4*)&Alds[row][c4] = p;
      }
    } else {
      const u16* X = (const u16*)Xv;
      #pragma unroll
      for (int i = 0; i < 4; ++i) {
        int f = (i << 8) + t;
        int row = f >> 3, c8 = (f & 7) << 3;
        *(u16x8*)&Alds[row][c8] =
            *(const u16x8*)(X + (size_t)(m0 + row) * 512 + k0 + c8);
      }
    }
    // ---- stage B tile [128][64] from W (always fp32) ----
    #pragma unroll
    for (int i = 0; i < 8; ++i) {
      int f = (i << 8) + t;
      int row = f >> 4, c4 = (f & 15) << 2;
      float4 x = *(const float4*)(W + (size_t)(n0 + row) * 512 + k0 + c4);
      u16x4 p = { f2bf(x.x), f2bf(x.y), f2bf(x.z), f2bf(x.w) };
      *(u16x4*)&Blds[row][c4] = p;
    }
    __syncthreads();

    #pragma unroll
    for (int kk = 0; kk < 2; ++kk) {
      bf16x8 af[4], bfr[4];
      #pragma unroll
      for (int mi = 0; mi < 4; ++mi)
        af[mi] = *(const bf16x8*)&Alds[(wr << 6) + (mi << 4) + lr][(kk << 5) + (lg << 3)];
      #pragma unroll
      for (int ni = 0; ni < 4; ++ni)
        bfr[ni] = *(const bf16x8*)&Blds[(wc << 6) + (ni << 4) + lr][(kk << 5) + (lg << 3)];
      #pragma unroll
      for (int mi = 0; mi < 4; ++mi)
        #pragma unroll
        for (int ni = 0; ni < 4; ++ni)
          acc[mi][ni] = __builtin_amdgcn_mfma_f32_16x16x32_bf16(af[mi], bfr[ni], acc[mi][ni], 0, 0, 0);
    }
    __syncthreads();
  }

  // ---- epilogue ----
  #pragma unroll
  for (int mi = 0; mi < 4; ++mi) {
    #pragma unroll
    for (int ni = 0; ni < 4; ++ni) {
      const int e = n0 + (wc << 6) + (ni << 4) + lr;
      const int m = m0 + (wr << 6) + (mi << 4) + (lg << 2);
      const float bb = bias[e];
      if (MODE == 0 || MODE == 1) {
        u16* O = (u16*)Outv;
        const int b = m >> 12, s = m & 4095, h = e >> 6, dk = e & 63;
        size_t base = ((size_t)((b << 3) + h) * SEQ + s) * DK + dk;
        #pragma unroll
        for (int r = 0; r < 4; ++r) {
          float val = acc[mi][ni][r] + bb;
          if (MODE == 0) val *= 0.125f;  // fold 1/sqrt(Dk); exact in bf16
          O[base + (size_t)r * DK] = f2bf(val);
        }
      } else if (MODE == 2) {
        u16* O = (u16*)Outv;
        const int b = m >> 12, s = m & 4095, h = e >> 6, dk = e & 63;
        size_t base = ((size_t)((b << 3) + h) * DK + dk) * SEQ + s;
        u16x4 p = { f2bf(acc[mi][ni][0] + bb), f2bf(acc[mi][ni][1] + bb),
                    f2bf(acc[mi][ni][2] + bb), f2bf(acc[mi][ni][3] + bb) };
        *(u16x4*)(O + base) = p;
      } else {
        float* O = (float*)Outv;
        size_t base = (size_t)m * 512 + e;
        #pragma unroll
        for (int r = 0; r < 4; ++r) O[base + (size_t)r * 512] = acc[mi][ni][r] + bb;
      }
    }
  }
}

// Flash attention. Grid: 16 (b,h) x 32 q-tiles of 128 rows. 4 waves x 32 q-rows.
__global__ __launch_bounds__(256, 2)
void attn_kernel(const u16* __restrict__ Qh, const u16* __restrict__ Kh,
                 const u16* __restrict__ Vt, u16* __restrict__ Xa)
{
  __shared__ alignas(16) u16 smem[64 * 72 * 2 + 4 * 16 * 72];
  u16* Klds = smem;               // [64][72]  row = kv, col = d
  u16* Vlds = smem + 64 * 72;     // [64][72]  row = d,  col = kv
  u16* Plds = smem + 2 * 64 * 72; // [4][16][72] per-wave P tile

  const int t = threadIdx.x;
  const int lane = t & 63, w = t >> 6;
  const int lr = lane & 15, lg = lane >> 4;
  const int qb = blockIdx.x & 31;
  const int bh = blockIdx.x >> 5;
  const size_t qkbase = (size_t)bh * SEQ * DK;
  const size_t vbase = (size_t)bh * DK * SEQ;

  // Q fragments in registers (rows w*32 + mi*16 + lr)
  bf16x8 qf[2][2];
  #pragma unroll
  for (int mi = 0; mi < 2; ++mi)
    #pragma unroll
    for (int kk = 0; kk < 2; ++kk) {
      int qrow = (qb << 7) + (w << 5) + (mi << 4) + lr;
      qf[mi][kk] = *(const bf16x8*)(Qh + qkbase + (size_t)qrow * DK + (kk << 5) + (lg << 3));
    }

  float mrun[2][4], lrun[2][4];
  f32x4 o[2][4];
  #pragma unroll
  for (int mi = 0; mi < 2; ++mi)
    #pragma unroll
    for (int r = 0; r < 4; ++r) { mrun[mi][r] = -1e30f; lrun[mi][r] = 0.f; }
  #pragma unroll
  for (int mi = 0; mi < 2; ++mi)
    #pragma unroll
    for (int dt = 0; dt < 4; ++dt) o[mi][dt] = (f32x4){0.f, 0.f, 0.f, 0.f};

  for (int kv0 = 0; kv0 < SEQ; kv0 += 64) {
    // stage K tile and Vt tile (each 64x64 bf16), coalesced 128B chunks
    {
      const int r = t >> 2, c = (t & 3) << 4;
      *(u16x8*)&Klds[r * 72 + c] =
          *(const u16x8*)(Kh + qkbase + (size_t)(kv0 + r) * DK + c);
      *(u16x8*)&Klds[r * 72 + c + 8] =
          *(const u16x8*)(Kh + qkbase + (size_t)(kv0 + r) * DK + c + 8);
      *(u16x8*)&Vlds[r * 72 + c] =
          *(const u16x8*)(Vt + vbase + (size_t)r * SEQ + kv0 + c);
      *(u16x8*)&Vlds[r * 72 + c + 8] =
          *(const u16x8*)(Vt + vbase + (size_t)r * SEQ + kv0 + c + 8);
    }
    __syncthreads();

    // hoist K/V fragments to registers; reused across both q-subtiles
    bf16x8 kf[4][2], vf[4][2];
    #pragma unroll
    for (int nt = 0; nt < 4; ++nt)
      #pragma unroll
      for (int kk = 0; kk < 2; ++kk) {
        kf[nt][kk] = *(const bf16x8*)&Klds[((nt << 4) + lr) * 72 + (kk << 5) + (lg << 3)];
        vf[nt][kk] = *(const bf16x8*)&Vlds[((nt << 4) + lr) * 72 + (kk << 5) + (lg << 3)];
      }

    #pragma unroll
    for (int mi = 0; mi < 2; ++mi) {
      f32x4 s[4];
      #pragma unroll
      for (int nt = 0; nt < 4; ++nt) s[nt] = (f32x4){0.f, 0.f, 0.f, 0.f};
      #pragma unroll
      for (int kk = 0; kk < 2; ++kk)
        #pragma unroll
        for (int nt = 0; nt < 4; ++nt)
          s[nt] = __builtin_amdgcn_mfma_f32_16x16x32_bf16(qf[mi][kk], kf[nt][kk], s[nt], 0, 0, 0);

      u16* P = Plds + w * 16 * 72;
      #pragma unroll
      for (int r = 0; r < 4; ++r) {
        float tmax = fmaxf(fmaxf(s[0][r], s[1][r]), fmaxf(s[2][r], s[3][r]));
        tmax = fmaxf(tmax, __shfl_xor(tmax, 1));
        tmax = fmaxf(tmax, __shfl_xor(tmax, 2));
        tmax = fmaxf(tmax, __shfl_xor(tmax, 4));
        tmax = fmaxf(tmax, __shfl_xor(tmax, 8));
        float mnew = fmaxf(mrun[mi][r], tmax);
        float scl = __expf(mrun[mi][r] - mnew);
        mrun[mi][r] = mnew;
        float psum = 0.f;
        #pragma unroll
        for (int nt = 0; nt < 4; ++nt) {
          float p = __expf(s[nt][r] - mnew);
          s[nt][r] = p;
          psum += p;
        }
        psum += __shfl_xor(psum, 1);
        psum += __shfl_xor(psum, 2);
        psum += __shfl_xor(psum, 4);
        psum += __shfl_xor(psum, 8);
        lrun[mi][r] = lrun[mi][r] * scl + psum;
        #pragma unroll
        for (int dt = 0; dt < 4; ++dt) o[mi][dt][r] *= scl;
        #pragma unroll
        for (int nt = 0; nt < 4; ++nt)
          P[((lg << 2) + r) * 72 + (nt << 4) + lr] = f2bf(s[nt][r]);
      }
      // PV: o += P * V  (contiguous A-frags from per-wave P tile)
      #pragma unroll
      for (int kk = 0; kk < 2; ++kk) {
        bf16x8 pf = *(const bf16x8*)&P[lr * 72 + (kk << 5) + (lg << 3)];
        #pragma unroll
        for (int dt = 0; dt < 4; ++dt)
          o[mi][dt] = __builtin_amdgcn_mfma_f32_16x16x32_bf16(pf, vf[dt][kk], o[mi][dt], 0, 0, 0);
      }
    }
    __syncthreads();
  }

  // normalize and write through LDS for coalesced bf16 stores
  #pragma unroll
  for (int mi = 0; mi < 2; ++mi)
    #pragma unroll
    for (int dt = 0; dt < 4; ++dt)
      #pragma unroll
      for (int r = 0; r < 4; ++r) {
        float val = o[mi][dt][r] / lrun[mi][r];
        int row = (w << 5) + (mi << 4) + (lg << 2) + r;
        smem[row * 72 + (dt << 4) + lr] = f2bf(val);
      }
  __syncthreads();
  {
    const int b = bh >> 3, h = bh & 7;
    #pragma unroll
    for (int i = 0; i < 4; ++i) {
      int f = (i << 8) + t;
      int row = f >> 3, c8 = (f & 7) << 3;
      u16x8 val = *(const u16x8*)&smem[row * 72 + c8];
      *(u16x8*)(Xa + ((size_t)b * SEQ + (qb << 7) + row) * D_MODEL + (h << 6) + c8) = val;
    }
  }
}

extern "C" void kernel_launch(void* const* d_in, const int* in_sizes, int n_in,
                              void* d_out, int out_size, void* d_ws, size_t ws_size,
                              hipStream_t stream)
{
  const float* q  = (const float*)d_in[0];
  const float* k  = (const float*)d_in[1];
  const float* v  = (const float*)d_in[2];
  const float* wq = (const float*)d_in[3];
  const float* bq = (const float*)d_in[4];
  const float* wk = (const float*)d_in[5];
  const float* bk = (const float*)d_in[6];
  const float* wv = (const float*)d_in[7];
  const float* bv = (const float*)d_in[8];
  const float* wo = (const float*)d_in[9];
  const float* bo = (const float*)d_in[10];

  const size_t HS = (size_t)BATCH * NHEAD * SEQ * DK;  // 4,194,304 elems
  u16* Qh = (u16*)d_ws;
  u16* Kh = Qh + HS;
  u16* Vt = Kh + HS;
  u16* Xa = Vt + HS;

  gemm_proj<0><<<256, 256, 0, stream>>>(q, wq, bq, Qh);
  gemm_proj<1><<<256, 256, 0, stream>>>(k, wk, bk, Kh);
  gemm_proj<2><<<256, 256, 0, stream>>>(v, wv, bv, Vt);
  attn_kernel<<<512, 256, 0, stream>>>(Qh, Kh, Vt, Xa);
  gemm_proj<3><<<256, 256, 0, stream>>>(Xa, wo, bo, (float*)d_out);
}

// Round 3
// 305.022 us; speedup vs baseline: 1.2817x; 1.2817x over previous
//
#include <hip/hip_runtime.h>

#define DM 512
#define NH 8
#define DK 64
#define SEQ 4096

typedef short bf16x8 __attribute__((ext_vector_type(8)));
typedef float f32x4 __attribute__((ext_vector_type(4)));
typedef unsigned short u16;
typedef u16 u16x8 __attribute__((ext_vector_type(8)));
typedef u16 u16x4 __attribute__((ext_vector_type(4)));
typedef unsigned int u32;
typedef u32 u32x2 __attribute__((ext_vector_type(2)));

__device__ __forceinline__ u16 f2bf(float f) {
  union { float f; unsigned u; } v; v.f = f;
  unsigned r = v.u + 0x7fffu + ((v.u >> 16) & 1u);
  return (u16)(r >> 16);
}

__device__ __forceinline__ u32 cvtpk(float a, float b) {
  u32 r; asm("v_cvt_pk_bf16_f32 %0, %1, %2" : "=v"(r) : "v"(a), "v"(b)); return r;
}

// ---- round-1 validated NT GEMM: C[m][e] = sum_d X[m][d]*W[e][d] + bias[e] ----
// 128x128 tiles, grid 256. MODE 0: fp32->bf16 Qh*0.125; 1: ->Kh; 2: ->Vt (transposed);
// 3: bf16->fp32 out.
template<int MODE>
__global__ __launch_bounds__(256, 2)
void gemm_proj(const void* __restrict__ Xv, const float* __restrict__ W,
               const float* __restrict__ bias, void* __restrict__ Outv)
{
  __shared__ alignas(16) u16 Alds[128][72];
  __shared__ alignas(16) u16 Blds[128][72];
  const int t = threadIdx.x;
  const int bx = blockIdx.x & 63;   // m tile
  const int by = blockIdx.x >> 6;   // n tile
  const int m0 = bx << 7, n0 = by << 7;
  const int lane = t & 63, w = t >> 6;
  const int lr = lane & 15, lg = lane >> 4;
  const int wr = w >> 1, wc = w & 1;

  f32x4 acc[4][4];
  #pragma unroll
  for (int i = 0; i < 4; ++i)
    #pragma unroll
    for (int j = 0; j < 4; ++j) acc[i][j] = (f32x4){0.f, 0.f, 0.f, 0.f};

  for (int k0 = 0; k0 < 512; k0 += 64) {
    if (MODE < 3) {
      const float* X = (const float*)Xv;
      #pragma unroll
      for (int i = 0; i < 8; ++i) {
        int f = (i << 8) + t;
        int row = f >> 4, c4 = (f & 15) << 2;
        float4 x = *(const float4*)(X + (size_t)(m0 + row) * 512 + k0 + c4);
        u16x4 p = { f2bf(x.x), f2bf(x.y), f2bf(x.z), f2bf(x.w) };
        *(u16x4*)&Alds[row][c4] = p;
      }
    } else {
      const u16* X = (const u16*)Xv;
      #pragma unroll
      for (int i = 0; i < 4; ++i) {
        int f = (i << 8) + t;
        int row = f >> 3, c8 = (f & 7) << 3;
        *(u16x8*)&Alds[row][c8] =
            *(const u16x8*)(X + (size_t)(m0 + row) * 512 + k0 + c8);
      }
    }
    #pragma unroll
    for (int i = 0; i < 8; ++i) {
      int f = (i << 8) + t;
      int row = f >> 4, c4 = (f & 15) << 2;
      float4 x = *(const float4*)(W + (size_t)(n0 + row) * 512 + k0 + c4);
      u16x4 p = { f2bf(x.x), f2bf(x.y), f2bf(x.z), f2bf(x.w) };
      *(u16x4*)&Blds[row][c4] = p;
    }
    __syncthreads();

    #pragma unroll
    for (int kk = 0; kk < 2; ++kk) {
      bf16x8 af[4], bfr[4];
      #pragma unroll
      for (int mi = 0; mi < 4; ++mi)
        af[mi] = *(const bf16x8*)&Alds[(wr << 6) + (mi << 4) + lr][(kk << 5) + (lg << 3)];
      #pragma unroll
      for (int ni = 0; ni < 4; ++ni)
        bfr[ni] = *(const bf16x8*)&Blds[(wc << 6) + (ni << 4) + lr][(kk << 5) + (lg << 3)];
      #pragma unroll
      for (int mi = 0; mi < 4; ++mi)
        #pragma unroll
        for (int ni = 0; ni < 4; ++ni)
          acc[mi][ni] = __builtin_amdgcn_mfma_f32_16x16x32_bf16(af[mi], bfr[ni], acc[mi][ni], 0, 0, 0);
    }
    __syncthreads();
  }

  #pragma unroll
  for (int mi = 0; mi < 4; ++mi) {
    #pragma unroll
    for (int ni = 0; ni < 4; ++ni) {
      const int e = n0 + (wc << 6) + (ni << 4) + lr;
      const int m = m0 + (wr << 6) + (mi << 4) + (lg << 2);
      const float bb = bias[e];
      if (MODE == 0 || MODE == 1) {
        u16* O = (u16*)Outv;
        const int b = m >> 12, s = m & 4095, h = e >> 6, dk = e & 63;
        size_t base = ((size_t)((b << 3) + h) * SEQ + s) * DK + dk;
        #pragma unroll
        for (int r = 0; r < 4; ++r) {
          float val = acc[mi][ni][r] + bb;
          if (MODE == 0) val *= 0.125f;
          O[base + (size_t)r * DK] = f2bf(val);
        }
      } else if (MODE == 2) {
        u16* O = (u16*)Outv;
        const int b = m >> 12, s = m & 4095, h = e >> 6, dk = e & 63;
        size_t base = ((size_t)((b << 3) + h) * DK + dk) * SEQ + s;
        u16x4 p = { f2bf(acc[mi][ni][0] + bb), f2bf(acc[mi][ni][1] + bb),
                    f2bf(acc[mi][ni][2] + bb), f2bf(acc[mi][ni][3] + bb) };
        *(u16x4*)(O + base) = p;
      } else {
        float* O = (float*)Outv;
        size_t base = (size_t)m * 512 + e;
        #pragma unroll
        for (int r = 0; r < 4; ++r) O[base + (size_t)r * 512] = acc[mi][ni][r] + bb;
      }
    }
  }
}

// Flash attention. Round-1 skeleton (staging, barriers, frag hoisting identical).
// ONE delta: swapped-operand MFMAs -> lane-local softmax (q = lane&15 domain).
__global__ __launch_bounds__(256, 2)
void attn_kernel(const u16* __restrict__ Qh, const u16* __restrict__ Kh,
                 const u16* __restrict__ Vt, u16* __restrict__ Xa)
{
  __shared__ alignas(16) u16 smem[64 * 72 * 2 + 4 * 16 * 72];
  u16* Klds = smem;               // [64][72]  row = kv, col = d
  u16* Vlds = smem + 64 * 72;     // [64][72]  row = d,  col = kv
  u16* Plds = smem + 2 * 64 * 72; // [4][16][72] per-wave P, row = q(lr), col = kv

  const int t = threadIdx.x;
  const int lane = t & 63, w = t >> 6;
  const int lr = lane & 15, lg = lane >> 4;
  const int ob = ((blockIdx.x & 7) << 6) + (blockIdx.x >> 3);  // XCD-bijective swizzle
  const int qb = ob & 31, bh = ob >> 5;
  const size_t qkbase = (size_t)bh * SEQ * DK;
  const size_t vbase  = (size_t)bh * DK * SEQ;
  u16* Pw = Plds + w * 16 * 72;

  // Q fragments (identical load to round 1; used as B-operand now)
  bf16x8 qf[2][2];
  #pragma unroll
  for (int mi = 0; mi < 2; ++mi)
    #pragma unroll
    for (int kk = 0; kk < 2; ++kk) {
      int qrow = (qb << 7) + (w << 5) + (mi << 4) + lr;
      qf[mi][kk] = *(const bf16x8*)(Qh + qkbase + (size_t)qrow * DK + (kk << 5) + (lg << 3));
    }

  float mrun[2] = {-3e38f, -3e38f}, lrun[2] = {0.f, 0.f};
  f32x4 o[2][4];
  #pragma unroll
  for (int mi = 0; mi < 2; ++mi)
    #pragma unroll
    for (int dt = 0; dt < 4; ++dt) o[mi][dt] = (f32x4){0.f, 0.f, 0.f, 0.f};

  for (int kv0 = 0; kv0 < SEQ; kv0 += 64) {
    // stage K tile and Vt tile (identical to round 1)
    {
      const int r = t >> 2, c = (t & 3) << 4;
      *(u16x8*)&Klds[r * 72 + c] =
          *(const u16x8*)(Kh + qkbase + (size_t)(kv0 + r) * DK + c);
      *(u16x8*)&Klds[r * 72 + c + 8] =
          *(const u16x8*)(Kh + qkbase + (size_t)(kv0 + r) * DK + c + 8);
      *(u16x8*)&Vlds[r * 72 + c] =
          *(const u16x8*)(Vt + vbase + (size_t)r * SEQ + kv0 + c);
      *(u16x8*)&Vlds[r * 72 + c + 8] =
          *(const u16x8*)(Vt + vbase + (size_t)r * SEQ + kv0 + c + 8);
    }
    __syncthreads();

    // hoist K/V fragments (identical loads to round 1)
    bf16x8 kf[4][2], vf[4][2];
    #pragma unroll
    for (int nt = 0; nt < 4; ++nt)
      #pragma unroll
      for (int kk = 0; kk < 2; ++kk) {
        kf[nt][kk] = *(const bf16x8*)&Klds[((nt << 4) + lr) * 72 + (kk << 5) + (lg << 3)];
        vf[nt][kk] = *(const bf16x8*)&Vlds[((nt << 4) + lr) * 72 + (kk << 5) + (lg << 3)];
      }

    #pragma unroll
    for (int mi = 0; mi < 2; ++mi) {
      // S^T = K * Q^T : lane holds q = lr, kv = nt*16 + lg*4 + r
      f32x4 s[4];
      #pragma unroll
      for (int nt = 0; nt < 4; ++nt) s[nt] = (f32x4){0.f, 0.f, 0.f, 0.f};
      #pragma unroll
      for (int kk = 0; kk < 2; ++kk)
        #pragma unroll
        for (int nt = 0; nt < 4; ++nt)
          s[nt] = __builtin_amdgcn_mfma_f32_16x16x32_bf16(kf[nt][kk], qf[mi][kk], s[nt], 0, 0, 0);

      // row max: 16 in-register values + 2 cross-lane hops (over lg)
      float tmax = fmaxf(fmaxf(s[0][0], s[0][1]), fmaxf(s[0][2], s[0][3]));
      #pragma unroll
      for (int nt = 1; nt < 4; ++nt)
        tmax = fmaxf(tmax, fmaxf(fmaxf(s[nt][0], s[nt][1]), fmaxf(s[nt][2], s[nt][3])));
      tmax = fmaxf(tmax, __shfl_xor(tmax, 16));
      tmax = fmaxf(tmax, __shfl_xor(tmax, 32));
      float mnew = fmaxf(mrun[mi], tmax);
      float scl = __expf(mrun[mi] - mnew);
      mrun[mi] = mnew;

      float psum = 0.f;
      #pragma unroll
      for (int nt = 0; nt < 4; ++nt) {
        float e0 = __expf(s[nt][0] - mnew), e1 = __expf(s[nt][1] - mnew);
        float e2 = __expf(s[nt][2] - mnew), e3 = __expf(s[nt][3] - mnew);
        psum += (e0 + e1) + (e2 + e3);
        u32x2 pk2 = { cvtpk(e0, e1), cvtpk(e2, e3) };
        // row q = lr, u16 col kv = nt*16 + lg*4 .. +4  (linear, no swizzle)
        *(u32x2*)((char*)Pw + lr * 144 + (nt << 5) + (lg << 3)) = pk2;
      }
      psum += __shfl_xor(psum, 16);
      psum += __shfl_xor(psum, 32);
      lrun[mi] = lrun[mi] * scl + psum;
      #pragma unroll
      for (int dt = 0; dt < 4; ++dt) o[mi][dt] *= scl;

      // O^T += V * P^T : lane needs P[q=lr][kv = kk*32 + lg*8 .. +8]
      #pragma unroll
      for (int kk = 0; kk < 2; ++kk) {
        bf16x8 pf = *(const bf16x8*)&Pw[lr * 72 + (kk << 5) + (lg << 3)];
        #pragma unroll
        for (int dt = 0; dt < 4; ++dt)
          o[mi][dt] = __builtin_amdgcn_mfma_f32_16x16x32_bf16(vf[dt][kk], pf, o[mi][dt], 0, 0, 0);
      }
    }
    __syncthreads();
  }

  // epilogue: lane holds O^T[d = dt*16+lg*4+r][q = lr]; stage in LDS, coalesced store
  #pragma unroll
  for (int mi = 0; mi < 2; ++mi) {
    float inv = 1.f / lrun[mi];
    #pragma unroll
    for (int dt = 0; dt < 4; ++dt) {
      u16x4 v4 = { f2bf(o[mi][dt][0] * inv), f2bf(o[mi][dt][1] * inv),
                   f2bf(o[mi][dt][2] * inv), f2bf(o[mi][dt][3] * inv) };
      int row = (w << 5) + (mi << 4) + lr;
      *(u16x4*)&smem[row * 72 + (dt << 4) + (lg << 2)] = v4;
    }
  }
  __syncthreads();
  {
    const int b = bh >> 3, h = bh & 7;
    #pragma unroll
    for (int i = 0; i < 4; ++i) {
      int f = (i << 8) + t;
      int row = f >> 3, c8 = (f & 7) << 3;
      u16x8 val = *(const u16x8*)&smem[row * 72 + c8];
      *(u16x8*)(Xa + ((size_t)b * SEQ + (qb << 7) + row) * DM + (h << 6) + c8) = val;
    }
  }
}

extern "C" void kernel_launch(void* const* d_in, const int* in_sizes, int n_in,
                              void* d_out, int out_size, void* d_ws, size_t ws_size,
                              hipStream_t stream)
{
  const float* q  = (const float*)d_in[0];
  const float* k  = (const float*)d_in[1];
  const float* v  = (const float*)d_in[2];
  const float* wq = (const float*)d_in[3];
  const float* bq = (const float*)d_in[4];
  const float* wk = (const float*)d_in[5];
  const float* bk = (const float*)d_in[6];
  const float* wv = (const float*)d_in[7];
  const float* bv = (const float*)d_in[8];
  const float* wo = (const float*)d_in[9];
  const float* bo = (const float*)d_in[10];

  const size_t HS = (size_t)2 * NH * SEQ * DK;
  u16* Qh = (u16*)d_ws;
  u16* Kh = Qh + HS;
  u16* Vt = Kh + HS;
  u16* Xa = Vt + HS;

  gemm_proj<0><<<256, 256, 0, stream>>>(q, wq, bq, Qh);
  gemm_proj<1><<<256, 256, 0, stream>>>(k, wk, bk, Kh);
  gemm_proj<2><<<256, 256, 0, stream>>>(v, wv, bv, Vt);
  attn_kernel<<<512, 256, 0, stream>>>(Qh, Kh, Vt, Xa);
  gemm_proj<3><<<256, 256, 0, stream>>>(Xa, wo, bo, (float*)d_out);
}

// Round 4
// 231.490 us; speedup vs baseline: 1.6888x; 1.3176x over previous
//
#include <hip/hip_runtime.h>

#define DM 512
#define NH 8
#define DK 64
#define SEQ 4096

typedef short bf16x8 __attribute__((ext_vector_type(8)));
typedef float f32x4 __attribute__((ext_vector_type(4)));
typedef unsigned short u16;
typedef u16 u16x8 __attribute__((ext_vector_type(8)));
typedef u16 u16x4 __attribute__((ext_vector_type(4)));
typedef unsigned int u32;
typedef u32 u32x2 __attribute__((ext_vector_type(2)));

__device__ __forceinline__ u16 f2bf(float f) {
  union { float f; unsigned u; } v; v.f = f;
  unsigned r = v.u + 0x7fffu + ((v.u >> 16) & 1u);
  return (u16)(r >> 16);
}

__device__ __forceinline__ u32 cvtpk(float a, float b) {
  u32 r; asm("v_cvt_pk_bf16_f32 %0, %1, %2" : "=v"(r) : "v"(a), "v"(b)); return r;
}

__device__ __forceinline__ float fexp2(float x) {
  float r; asm("v_exp_f32 %0, %1" : "=v"(r) : "v"(x)); return r;
}

// NT GEMM: C[m][e] = sum_d X[m][d]*W[e][d] + bias[e]; M=8192, N=K=512.
// 64x128 tiles -> grid 512 (2 blocks/CU). 4 waves: wave tile 32x64 (acc[2][4]).
// MODE 0: fp32 -> bf16 Qh[b][h][s][dk] * (0.125*log2(e))   [exp2-domain scores]
// MODE 1: fp32 -> bf16 Kh
// MODE 2: fp32 -> bf16 Vt[b][h][dk][s]  (transposed)
// MODE 3: bf16 -> fp32 [b][s][e]
template<int MODE>
__global__ __launch_bounds__(256, 2)
void gemm_proj(const void* __restrict__ Xv, const float* __restrict__ W,
               const float* __restrict__ bias, void* __restrict__ Outv)
{
  __shared__ alignas(16) u16 Alds[64][72];
  __shared__ alignas(16) u16 Blds[128][72];
  const int t = threadIdx.x;
  const int bx = blockIdx.x & 127;  // m tile (128 of them, 64 rows each)
  const int by = blockIdx.x >> 7;   // n tile (4, 128 cols each)
  const int m0 = bx << 6, n0 = by << 7;
  const int lane = t & 63, w = t >> 6;
  const int lr = lane & 15, lg = lane >> 4;
  const int wr = w >> 1, wc = w & 1;

  f32x4 acc[2][4];
  #pragma unroll
  for (int i = 0; i < 2; ++i)
    #pragma unroll
    for (int j = 0; j < 4; ++j) acc[i][j] = (f32x4){0.f, 0.f, 0.f, 0.f};

  for (int k0 = 0; k0 < 512; k0 += 64) {
    if (MODE < 3) {
      const float* X = (const float*)Xv;
      #pragma unroll
      for (int i = 0; i < 4; ++i) {
        int f = (i << 8) + t;
        int row = f >> 4, c4 = (f & 15) << 2;
        float4 x = *(const float4*)(X + (size_t)(m0 + row) * 512 + k0 + c4);
        u16x4 p = { f2bf(x.x), f2bf(x.y), f2bf(x.z), f2bf(x.w) };
        *(u16x4*)&Alds[row][c4] = p;
      }
    } else {
      const u16* X = (const u16*)Xv;
      #pragma unroll
      for (int i = 0; i < 2; ++i) {
        int f = (i << 8) + t;
        int row = f >> 3, c8 = (f & 7) << 3;
        *(u16x8*)&Alds[row][c8] =
            *(const u16x8*)(X + (size_t)(m0 + row) * 512 + k0 + c8);
      }
    }
    #pragma unroll
    for (int i = 0; i < 8; ++i) {
      int f = (i << 8) + t;
      int row = f >> 4, c4 = (f & 15) << 2;
      float4 x = *(const float4*)(W + (size_t)(n0 + row) * 512 + k0 + c4);
      u16x4 p = { f2bf(x.x), f2bf(x.y), f2bf(x.z), f2bf(x.w) };
      *(u16x4*)&Blds[row][c4] = p;
    }
    __syncthreads();

    #pragma unroll
    for (int kk = 0; kk < 2; ++kk) {
      bf16x8 af[2], bfr[4];
      #pragma unroll
      for (int mi = 0; mi < 2; ++mi)
        af[mi] = *(const bf16x8*)&Alds[(wr << 5) + (mi << 4) + lr][(kk << 5) + (lg << 3)];
      #pragma unroll
      for (int ni = 0; ni < 4; ++ni)
        bfr[ni] = *(const bf16x8*)&Blds[(wc << 6) + (ni << 4) + lr][(kk << 5) + (lg << 3)];
      #pragma unroll
      for (int mi = 0; mi < 2; ++mi)
        #pragma unroll
        for (int ni = 0; ni < 4; ++ni)
          acc[mi][ni] = __builtin_amdgcn_mfma_f32_16x16x32_bf16(af[mi], bfr[ni], acc[mi][ni], 0, 0, 0);
    }
    __syncthreads();
  }

  #pragma unroll
  for (int mi = 0; mi < 2; ++mi) {
    #pragma unroll
    for (int ni = 0; ni < 4; ++ni) {
      const int e = n0 + (wc << 6) + (ni << 4) + lr;
      const int m = m0 + (wr << 5) + (mi << 4) + (lg << 2);
      const float bb = bias[e];
      if (MODE == 0 || MODE == 1) {
        u16* O = (u16*)Outv;
        const int b = m >> 12, s = m & 4095, h = e >> 6, dk = e & 63;
        size_t base = ((size_t)((b << 3) + h) * SEQ + s) * DK + dk;
        #pragma unroll
        for (int r = 0; r < 4; ++r) {
          float val = acc[mi][ni][r] + bb;
          if (MODE == 0) val *= 0.18033688f;  // 0.125 * log2(e)
          O[base + (size_t)r * DK] = f2bf(val);
        }
      } else if (MODE == 2) {
        u16* O = (u16*)Outv;
        const int b = m >> 12, s = m & 4095, h = e >> 6, dk = e & 63;
        size_t base = ((size_t)((b << 3) + h) * DK + dk) * SEQ + s;
        u16x4 p = { f2bf(acc[mi][ni][0] + bb), f2bf(acc[mi][ni][1] + bb),
                    f2bf(acc[mi][ni][2] + bb), f2bf(acc[mi][ni][3] + bb) };
        *(u16x4*)(O + base) = p;
      } else {
        float* O = (float*)Outv;
        size_t base = (size_t)m * 512 + e;
        #pragma unroll
        for (int r = 0; r < 4; ++r) O[base + (size_t)r * 512] = acc[mi][ni][r] + bb;
      }
    }
  }
}

// Flash attention (round-3 skeleton). Deltas: K/V XOR-swizzled 128B-row LDS,
// reg-prefetch split staging, exp2 softmax, defer-max THR=8.
__global__ __launch_bounds__(256, 2)
void attn_kernel(const u16* __restrict__ Qh, const u16* __restrict__ Kh,
                 const u16* __restrict__ Vt, u16* __restrict__ Xa)
{
  // [0..4095] K [64 kv][64 d] swizzled   [4096..8191] V [64 d][64 kv] swizzled
  // [8192..12799] P: 4 waves x 16 x 72 (padded, validated)
  __shared__ alignas(16) u16 smem[12800];

  const int t = threadIdx.x;
  const int lane = t & 63, w = t >> 6;
  const int lr = lane & 15, lg = lane >> 4;
  const int ob = ((blockIdx.x & 7) << 6) + (blockIdx.x >> 3);  // XCD-bijective (512%8==0)
  const int qb = ob & 31, bh = ob >> 5;
  const size_t qkbase = (size_t)bh * SEQ * DK;
  const size_t vbase  = (size_t)bh * DK * SEQ;
  u16* Pw = smem + 8192 + w * 1152;

  // Q fragments (B-operand): q-row = mi*16+lr, k-slice = lg*8
  bf16x8 qf[2][2];
  #pragma unroll
  for (int mi = 0; mi < 2; ++mi)
    #pragma unroll
    for (int kk = 0; kk < 2; ++kk) {
      int qrow = (qb << 7) + (w << 5) + (mi << 4) + lr;
      qf[mi][kk] = *(const bf16x8*)(Qh + qkbase + (size_t)qrow * DK + (kk << 5) + (lg << 3));
    }

  float mrun[2] = {-3e38f, -3e38f}, lrun[2] = {0.f, 0.f};
  f32x4 o[2][4];
  #pragma unroll
  for (int mi = 0; mi < 2; ++mi)
    #pragma unroll
    for (int dt = 0; dt < 4; ++dt) o[mi][dt] = (f32x4){0.f, 0.f, 0.f, 0.f};

  // staging geometry: 512 granules of 16B per 64x64 tile, 2 per thread
  const u16* Kg = Kh + qkbase;
  const u16* Vg = Vt + vbase;
  const int g0 = t, g1 = t + 256;
  const int r0 = g0 >> 3, c0 = g0 & 7;
  const int r1 = g1 >> 3, c1 = g1 & 7;
  const int wk0 = r0 * 64 + ((c0 ^ (r0 & 7)) << 3);  // swizzled LDS offsets (u16)
  const int wk1 = r1 * 64 + ((c1 ^ (r1 & 7)) << 3);

  u16x8 kr0, kr1, vr0, vr1;
  kr0 = *(const u16x8*)(Kg + (size_t)r0 * 64 + (c0 << 3));
  kr1 = *(const u16x8*)(Kg + (size_t)r1 * 64 + (c1 << 3));
  vr0 = *(const u16x8*)(Vg + (size_t)r0 * SEQ + (c0 << 3));
  vr1 = *(const u16x8*)(Vg + (size_t)r1 * SEQ + (c1 << 3));

  for (int it = 0; it < SEQ / 64; ++it) {
    __syncthreads();  // all waves done reading previous K/V
    *(u16x8*)&smem[wk0]        = kr0;
    *(u16x8*)&smem[wk1]        = kr1;
    *(u16x8*)&smem[4096 + wk0] = vr0;
    *(u16x8*)&smem[4096 + wk1] = vr1;
    __syncthreads();
    if (it + 1 < SEQ / 64) {  // prefetch next tile into regs; hidden under compute
      const int kv0n = (it + 1) << 6;
      kr0 = *(const u16x8*)(Kg + (size_t)(kv0n + r0) * 64 + (c0 << 3));
      kr1 = *(const u16x8*)(Kg + (size_t)(kv0n + r1) * 64 + (c1 << 3));
      vr0 = *(const u16x8*)(Vg + (size_t)r0 * SEQ + kv0n + (c0 << 3));
      vr1 = *(const u16x8*)(Vg + (size_t)r1 * SEQ + kv0n + (c1 << 3));
    }

    // hoist K/V fragments (swizzled reads; conflict-free per 8-lane phase)
    bf16x8 kf[4][2], vf[4][2];
    #pragma unroll
    for (int nt = 0; nt < 4; ++nt)
      #pragma unroll
      for (int kk = 0; kk < 2; ++kk) {
        const int off = ((nt << 4) + lr) * 64 + ((((kk << 2) + lg) ^ (lr & 7)) << 3);
        kf[nt][kk] = *(const bf16x8*)&smem[off];
        vf[nt][kk] = *(const bf16x8*)&smem[4096 + off];
      }

    #pragma unroll
    for (int mi = 0; mi < 2; ++mi) {
      // S^T = K * Q^T : lane holds q = lr, kv = nt*16 + lg*4 + r  (exp2 domain)
      f32x4 s[4];
      #pragma unroll
      for (int nt = 0; nt < 4; ++nt) s[nt] = (f32x4){0.f, 0.f, 0.f, 0.f};
      #pragma unroll
      for (int kk = 0; kk < 2; ++kk)
        #pragma unroll
        for (int nt = 0; nt < 4; ++nt)
          s[nt] = __builtin_amdgcn_mfma_f32_16x16x32_bf16(kf[nt][kk], qf[mi][kk], s[nt], 0, 0, 0);

      float tmax = fmaxf(fmaxf(s[0][0], s[0][1]), fmaxf(s[0][2], s[0][3]));
      #pragma unroll
      for (int nt = 1; nt < 4; ++nt)
        tmax = fmaxf(tmax, fmaxf(fmaxf(s[nt][0], s[nt][1]), fmaxf(s[nt][2], s[nt][3])));
      tmax = fmaxf(tmax, __shfl_xor(tmax, 16));
      tmax = fmaxf(tmax, __shfl_xor(tmax, 32));

      // defer-max: rescale only when some row's max grew past THR=8 (P <= 2^8)
      if (!__all(tmax <= mrun[mi] + 8.f)) {
        float mnew = fmaxf(mrun[mi], tmax);
        float scl = fexp2(mrun[mi] - mnew);
        mrun[mi] = mnew;
        lrun[mi] *= scl;
        #pragma unroll
        for (int dt = 0; dt < 4; ++dt) o[mi][dt] *= scl;
      }
      const float mm = mrun[mi];

      float psum = 0.f;
      #pragma unroll
      for (int nt = 0; nt < 4; ++nt) {
        float e0 = fexp2(s[nt][0] - mm), e1 = fexp2(s[nt][1] - mm);
        float e2 = fexp2(s[nt][2] - mm), e3 = fexp2(s[nt][3] - mm);
        psum += (e0 + e1) + (e2 + e3);
        u32x2 pk2 = { cvtpk(e0, e1), cvtpk(e2, e3) };
        *(u32x2*)((char*)Pw + lr * 144 + (nt << 5) + (lg << 3)) = pk2;
      }
      psum += __shfl_xor(psum, 16);
      psum += __shfl_xor(psum, 32);
      lrun[mi] += psum;

      // O^T += V * P^T : lane holds q = lr, d = dt*16 + lg*4 + r
      #pragma unroll
      for (int kk = 0; kk < 2; ++kk) {
        bf16x8 pf = *(const bf16x8*)&Pw[lr * 72 + (kk << 5) + (lg << 3)];
        #pragma unroll
        for (int dt = 0; dt < 4; ++dt)
          o[mi][dt] = __builtin_amdgcn_mfma_f32_16x16x32_bf16(vf[dt][kk], pf, o[mi][dt], 0, 0, 0);
      }
    }
  }
  __syncthreads();  // all waves done with K/V/P before smem reuse

  // epilogue: stage bf16 tile [128][72], then coalesced store
  #pragma unroll
  for (int mi = 0; mi < 2; ++mi) {
    float inv = 1.f / lrun[mi];
    #pragma unroll
    for (int dt = 0; dt < 4; ++dt) {
      u16x4 v4 = { f2bf(o[mi][dt][0] * inv), f2bf(o[mi][dt][1] * inv),
                   f2bf(o[mi][dt][2] * inv), f2bf(o[mi][dt][3] * inv) };
      int row = (w << 5) + (mi << 4) + lr;
      *(u16x4*)&smem[row * 72 + (dt << 4) + (lg << 2)] = v4;
    }
  }
  __syncthreads();
  {
    const int b = bh >> 3, h = bh & 7;
    #pragma unroll
    for (int i = 0; i < 4; ++i) {
      int f = (i << 8) + t;
      int row = f >> 3, c8 = (f & 7) << 3;
      u16x8 val = *(const u16x8*)&smem[row * 72 + c8];
      *(u16x8*)(Xa + ((size_t)b * SEQ + (qb << 7) + row) * DM + (h << 6) + c8) = val;
    }
  }
}

extern "C" void kernel_launch(void* const* d_in, const int* in_sizes, int n_in,
                              void* d_out, int out_size, void* d_ws, size_t ws_size,
                              hipStream_t stream)
{
  const float* q  = (const float*)d_in[0];
  const float* k  = (const float*)d_in[1];
  const float* v  = (const float*)d_in[2];
  const float* wq = (const float*)d_in[3];
  const float* bq = (const float*)d_in[4];
  const float* wk = (const float*)d_in[5];
  const float* bk = (const float*)d_in[6];
  const float* wv = (const float*)d_in[7];
  const float* bv = (const float*)d_in[8];
  const float* wo = (const float*)d_in[9];
  const float* bo = (const float*)d_in[10];

  const size_t HS = (size_t)2 * NH * SEQ * DK;
  u16* Qh = (u16*)d_ws;
  u16* Kh = Qh + HS;
  u16* Vt = Kh + HS;
  u16* Xa = Vt + HS;

  gemm_proj<0><<<512, 256, 0, stream>>>(q, wq, bq, Qh);
  gemm_proj<1><<<512, 256, 0, stream>>>(k, wk, bk, Kh);
  gemm_proj<2><<<512, 256, 0, stream>>>(v, wv, bv, Vt);
  attn_kernel<<<512, 256, 0, stream>>>(Qh, Kh, Vt, Xa);
  gemm_proj<3><<<512, 256, 0, stream>>>(Xa, wo, bo, (float*)d_out);
}

// Round 5
// 174.670 us; speedup vs baseline: 2.2381x; 1.3253x over previous
//
#include <hip/hip_runtime.h>

#define DM 512
#define NH 8
#define DK 64
#define SEQ 4096

typedef short bf16x8 __attribute__((ext_vector_type(8)));
typedef float f32x4 __attribute__((ext_vector_type(4)));
typedef unsigned short u16;
typedef u16 u16x8 __attribute__((ext_vector_type(8)));
typedef u16 u16x4 __attribute__((ext_vector_type(4)));
typedef unsigned int u32;
typedef u32 u32x2 __attribute__((ext_vector_type(2)));

__device__ __forceinline__ u16 f2bf(float f) {
  union { float f; unsigned u; } v; v.f = f;
  unsigned r = v.u + 0x7fffu + ((v.u >> 16) & 1u);
  return (u16)(r >> 16);
}

__device__ __forceinline__ u32 cvtpk(float a, float b) {
  u32 r; asm("v_cvt_pk_bf16_f32 %0, %1, %2" : "=v"(r) : "v"(a), "v"(b)); return r;
}

__device__ __forceinline__ float fexp2(float x) {
  float r; asm("v_exp_f32 %0, %1" : "=v"(r) : "v"(x)); return r;
}

// NT GEMM: C[m][e] = sum_d X[m][d]*W[e][d] + bias[e]; M=8192, N=K=512.
// 64x128 tiles, grid 512 (2 blocks/CU). Reg-prefetch split staging (T14).
// MODE 0: fp32 -> bf16 Qh[b][h][s][dk] * (0.125*log2(e))
// MODE 1: fp32 -> bf16 Kh
// MODE 2: fp32 -> bf16 Vt[b][h][dk][s]  (transposed)
// MODE 3: bf16 -> fp32 [b][s][e]
template<int MODE>
__global__ __launch_bounds__(256, 2)
void gemm_proj(const void* __restrict__ Xv, const float* __restrict__ W,
               const float* __restrict__ bias, void* __restrict__ Outv)
{
  __shared__ alignas(16) u16 Alds[64][72];
  __shared__ alignas(16) u16 Blds[128][72];
  const int t = threadIdx.x;
  const int bx = blockIdx.x & 127;  // m tile (128 of them, 64 rows)
  const int by = blockIdx.x >> 7;   // n tile (4, 128 cols)
  const int m0 = bx << 6, n0 = by << 7;
  const int lane = t & 63, w = t >> 6;
  const int lr = lane & 15, lg = lane >> 4;
  const int wr = w >> 1, wc = w & 1;

  f32x4 acc[2][4];
  #pragma unroll
  for (int i = 0; i < 2; ++i)
    #pragma unroll
    for (int j = 0; j < 4; ++j) acc[i][j] = (f32x4){0.f, 0.f, 0.f, 0.f};

  // per-thread staging coords (loop-invariant)
  float4 xa[4]; u16x8 xa3[2]; float4 wb[8];

  auto loadX = [&](int k0) {
    if (MODE < 3) {
      const float* X = (const float*)Xv;
      #pragma unroll
      for (int i = 0; i < 4; ++i) {
        int f = (i << 8) + t;
        xa[i] = *(const float4*)(X + (size_t)(m0 + (f >> 4)) * 512 + k0 + ((f & 15) << 2));
      }
    } else {
      const u16* X = (const u16*)Xv;
      #pragma unroll
      for (int i = 0; i < 2; ++i) {
        int f = (i << 8) + t;
        xa3[i] = *(const u16x8*)(X + (size_t)(m0 + (f >> 3)) * 512 + k0 + ((f & 7) << 3));
      }
    }
    #pragma unroll
    for (int i = 0; i < 8; ++i) {
      int f = (i << 8) + t;
      wb[i] = *(const float4*)(W + (size_t)(n0 + (f >> 4)) * 512 + k0 + ((f & 15) << 2));
    }
  };

  loadX(0);
  for (int k0 = 0; k0 < 512; k0 += 64) {
    __syncthreads();  // all waves done reading LDS from previous k-step
    if (MODE < 3) {
      #pragma unroll
      for (int i = 0; i < 4; ++i) {
        int f = (i << 8) + t;
        u16x4 p = { f2bf(xa[i].x), f2bf(xa[i].y), f2bf(xa[i].z), f2bf(xa[i].w) };
        *(u16x4*)&Alds[f >> 4][(f & 15) << 2] = p;
      }
    } else {
      #pragma unroll
      for (int i = 0; i < 2; ++i) {
        int f = (i << 8) + t;
        *(u16x8*)&Alds[f >> 3][(f & 7) << 3] = xa3[i];
      }
    }
    #pragma unroll
    for (int i = 0; i < 8; ++i) {
      int f = (i << 8) + t;
      u16x4 p = { f2bf(wb[i].x), f2bf(wb[i].y), f2bf(wb[i].z), f2bf(wb[i].w) };
      *(u16x4*)&Blds[f >> 4][(f & 15) << 2] = p;
    }
    __syncthreads();
    if (k0 + 64 < 512) loadX(k0 + 64);  // prefetch hides under MFMA

    #pragma unroll
    for (int kk = 0; kk < 2; ++kk) {
      bf16x8 af[2], bfr[4];
      #pragma unroll
      for (int mi = 0; mi < 2; ++mi)
        af[mi] = *(const bf16x8*)&Alds[(wr << 5) + (mi << 4) + lr][(kk << 5) + (lg << 3)];
      #pragma unroll
      for (int ni = 0; ni < 4; ++ni)
        bfr[ni] = *(const bf16x8*)&Blds[(wc << 6) + (ni << 4) + lr][(kk << 5) + (lg << 3)];
      #pragma unroll
      for (int mi = 0; mi < 2; ++mi)
        #pragma unroll
        for (int ni = 0; ni < 4; ++ni)
          acc[mi][ni] = __builtin_amdgcn_mfma_f32_16x16x32_bf16(af[mi], bfr[ni], acc[mi][ni], 0, 0, 0);
    }
  }

  #pragma unroll
  for (int mi = 0; mi < 2; ++mi) {
    #pragma unroll
    for (int ni = 0; ni < 4; ++ni) {
      const int e = n0 + (wc << 6) + (ni << 4) + lr;
      const int m = m0 + (wr << 5) + (mi << 4) + (lg << 2);
      const float bb = bias[e];
      if (MODE == 0 || MODE == 1) {
        u16* O = (u16*)Outv;
        const int b = m >> 12, s = m & 4095, h = e >> 6, dk = e & 63;
        size_t base = ((size_t)((b << 3) + h) * SEQ + s) * DK + dk;
        #pragma unroll
        for (int r = 0; r < 4; ++r) {
          float val = acc[mi][ni][r] + bb;
          if (MODE == 0) val *= 0.18033688f;  // 0.125 * log2(e)
          O[base + (size_t)r * DK] = f2bf(val);
        }
      } else if (MODE == 2) {
        u16* O = (u16*)Outv;
        const int b = m >> 12, s = m & 4095, h = e >> 6, dk = e & 63;
        size_t base = ((size_t)((b << 3) + h) * DK + dk) * SEQ + s;
        u16x4 p = { f2bf(acc[mi][ni][0] + bb), f2bf(acc[mi][ni][1] + bb),
                    f2bf(acc[mi][ni][2] + bb), f2bf(acc[mi][ni][3] + bb) };
        *(u16x4*)(O + base) = p;
      } else {
        float* O = (float*)Outv;
        size_t base = (size_t)m * 512 + e;
        #pragma unroll
        for (int r = 0; r < 4; ++r) O[base + (size_t)r * 512] = acc[mi][ni][r] + bb;
      }
    }
  }
}

// Flash attention (round-4 structure, q-tile 64). Grid 1024 = 16 bh x 64 q-tiles
// -> 4 blocks/CU for latency hiding. Each wave: 16 q-rows.
__global__ __launch_bounds__(256, 4)
void attn_kernel(const u16* __restrict__ Qh, const u16* __restrict__ Kh,
                 const u16* __restrict__ Vt, u16* __restrict__ Xa)
{
  // [0..4095] K [64 kv][64 d] swizzled; [4096..8191] V [64 d][64 kv] swizzled
  // [8192..12799] P: 4 waves x 16 x 72 (padded)
  __shared__ alignas(16) u16 smem[12800];

  const int t = threadIdx.x;
  const int lane = t & 63, w = t >> 6;
  const int lr = lane & 15, lg = lane >> 4;
  const int ob = ((blockIdx.x & 7) << 7) + (blockIdx.x >> 3);  // XCD-bijective (1024%8==0)
  const int qb = ob & 63, bh = ob >> 6;  // each XCD -> 2 heads (K+V 2MB fits L2)
  const size_t qkbase = (size_t)bh * SEQ * DK;
  const size_t vbase  = (size_t)bh * DK * SEQ;
  u16* Pw = smem + 8192 + w * 1152;

  // Q fragments (B-operand): q-row = w*16+lr, k-slice = kk*32+lg*8
  bf16x8 qf[2];
  #pragma unroll
  for (int kk = 0; kk < 2; ++kk) {
    int qrow = (qb << 6) + (w << 4) + lr;
    qf[kk] = *(const bf16x8*)(Qh + qkbase + (size_t)qrow * DK + (kk << 5) + (lg << 3));
  }

  float mrun = -3e38f, lrun = 0.f;
  f32x4 o[4];
  #pragma unroll
  for (int dt = 0; dt < 4; ++dt) o[dt] = (f32x4){0.f, 0.f, 0.f, 0.f};

  // staging: 512 granules of 16B per 64x64 tile, 2 per thread
  const u16* Kg = Kh + qkbase;
  const u16* Vg = Vt + vbase;
  const int r0 = t >> 3, c0 = t & 7;
  const int r1 = r0 + 32, c1 = c0;
  const int wk0 = r0 * 64 + ((c0 ^ (r0 & 7)) << 3);  // swizzled LDS (u16 units)
  const int wk1 = r1 * 64 + ((c1 ^ (r1 & 7)) << 3);

  u16x8 kr0, kr1, vr0, vr1;
  kr0 = *(const u16x8*)(Kg + (size_t)r0 * 64 + (c0 << 3));
  kr1 = *(const u16x8*)(Kg + (size_t)r1 * 64 + (c1 << 3));
  vr0 = *(const u16x8*)(Vg + (size_t)r0 * SEQ + (c0 << 3));
  vr1 = *(const u16x8*)(Vg + (size_t)r1 * SEQ + (c1 << 3));

  for (int it = 0; it < SEQ / 64; ++it) {
    __syncthreads();  // all waves done reading previous K/V
    *(u16x8*)&smem[wk0]        = kr0;
    *(u16x8*)&smem[wk1]        = kr1;
    *(u16x8*)&smem[4096 + wk0] = vr0;
    *(u16x8*)&smem[4096 + wk1] = vr1;
    __syncthreads();
    if (it + 1 < SEQ / 64) {  // prefetch next tile; hidden under compute
      const int kv0n = (it + 1) << 6;
      kr0 = *(const u16x8*)(Kg + (size_t)(kv0n + r0) * 64 + (c0 << 3));
      kr1 = *(const u16x8*)(Kg + (size_t)(kv0n + r1) * 64 + (c1 << 3));
      vr0 = *(const u16x8*)(Vg + (size_t)r0 * SEQ + kv0n + (c0 << 3));
      vr1 = *(const u16x8*)(Vg + (size_t)r1 * SEQ + kv0n + (c1 << 3));
    }

    // hoist K/V fragments (swizzled, conflict-free)
    bf16x8 kf[4][2], vf[4][2];
    #pragma unroll
    for (int nt = 0; nt < 4; ++nt)
      #pragma unroll
      for (int kk = 0; kk < 2; ++kk) {
        const int off = ((nt << 4) + lr) * 64 + ((((kk << 2) + lg) ^ (lr & 7)) << 3);
        kf[nt][kk] = *(const bf16x8*)&smem[off];
        vf[nt][kk] = *(const bf16x8*)&smem[4096 + off];
      }

    // S^T = K * Q^T : lane holds q = lr, kv = nt*16 + lg*4 + r  (exp2 domain)
    f32x4 s[4];
    #pragma unroll
    for (int nt = 0; nt < 4; ++nt) s[nt] = (f32x4){0.f, 0.f, 0.f, 0.f};
    #pragma unroll
    for (int kk = 0; kk < 2; ++kk)
      #pragma unroll
      for (int nt = 0; nt < 4; ++nt)
        s[nt] = __builtin_amdgcn_mfma_f32_16x16x32_bf16(kf[nt][kk], qf[kk], s[nt], 0, 0, 0);

    float tmax = fmaxf(fmaxf(s[0][0], s[0][1]), fmaxf(s[0][2], s[0][3]));
    #pragma unroll
    for (int nt = 1; nt < 4; ++nt)
      tmax = fmaxf(tmax, fmaxf(fmaxf(s[nt][0], s[nt][1]), fmaxf(s[nt][2], s[nt][3])));
    tmax = fmaxf(tmax, __shfl_xor(tmax, 16));
    tmax = fmaxf(tmax, __shfl_xor(tmax, 32));

    // defer-max: rescale only when some row's max grew past THR=8 (P <= 2^8)
    if (!__all(tmax <= mrun + 8.f)) {
      float mnew = fmaxf(mrun, tmax);
      float scl = fexp2(mrun - mnew);
      mrun = mnew;
      lrun *= scl;
      #pragma unroll
      for (int dt = 0; dt < 4; ++dt) o[dt] *= scl;
    }
    const float mm = mrun;

    float psum = 0.f;
    #pragma unroll
    for (int nt = 0; nt < 4; ++nt) {
      float e0 = fexp2(s[nt][0] - mm), e1 = fexp2(s[nt][1] - mm);
      float e2 = fexp2(s[nt][2] - mm), e3 = fexp2(s[nt][3] - mm);
      psum += (e0 + e1) + (e2 + e3);
      u32x2 pk2 = { cvtpk(e0, e1), cvtpk(e2, e3) };
      *(u32x2*)((char*)Pw + lr * 144 + (nt << 5) + (lg << 3)) = pk2;
    }
    psum += __shfl_xor(psum, 16);
    psum += __shfl_xor(psum, 32);
    lrun += psum;

    // O^T += V * P^T : lane holds q = lr, d = dt*16 + lg*4 + r
    #pragma unroll
    for (int kk = 0; kk < 2; ++kk) {
      bf16x8 pf = *(const bf16x8*)&Pw[lr * 72 + (kk << 5) + (lg << 3)];
      #pragma unroll
      for (int dt = 0; dt < 4; ++dt)
        o[dt] = __builtin_amdgcn_mfma_f32_16x16x32_bf16(vf[dt][kk], pf, o[dt], 0, 0, 0);
    }
  }
  __syncthreads();  // all waves done with K/V/P before smem reuse

  // epilogue: stage bf16 tile [64][72], then coalesced store
  {
    float inv = 1.f / lrun;
    #pragma unroll
    for (int dt = 0; dt < 4; ++dt) {
      u16x4 v4 = { f2bf(o[dt][0] * inv), f2bf(o[dt][1] * inv),
                   f2bf(o[dt][2] * inv), f2bf(o[dt][3] * inv) };
      int row = (w << 4) + lr;
      *(u16x4*)&smem[row * 72 + (dt << 4) + (lg << 2)] = v4;
    }
  }
  __syncthreads();
  {
    const int b = bh >> 3, h = bh & 7;
    #pragma unroll
    for (int i = 0; i < 2; ++i) {
      int f = (i << 8) + t;
      int row = f >> 3, c8 = (f & 7) << 3;
      u16x8 val = *(const u16x8*)&smem[row * 72 + c8];
      *(u16x8*)(Xa + ((size_t)b * SEQ + (qb << 6) + row) * DM + (h << 6) + c8) = val;
    }
  }
}

extern "C" void kernel_launch(void* const* d_in, const int* in_sizes, int n_in,
                              void* d_out, int out_size, void* d_ws, size_t ws_size,
                              hipStream_t stream)
{
  const float* q  = (const float*)d_in[0];
  const float* k  = (const float*)d_in[1];
  const float* v  = (const float*)d_in[2];
  const float* wq = (const float*)d_in[3];
  const float* bq = (const float*)d_in[4];
  const float* wk = (const float*)d_in[5];
  const float* bk = (const float*)d_in[6];
  const float* wv = (const float*)d_in[7];
  const float* bv = (const float*)d_in[8];
  const float* wo = (const float*)d_in[9];
  const float* bo = (const float*)d_in[10];

  const size_t HS = (size_t)2 * NH * SEQ * DK;
  u16* Qh = (u16*)d_ws;
  u16* Kh = Qh + HS;
  u16* Vt = Kh + HS;
  u16* Xa = Vt + HS;

  gemm_proj<0><<<512, 256, 0, stream>>>(q, wq, bq, Qh);
  gemm_proj<1><<<512, 256, 0, stream>>>(k, wk, bk, Kh);
  gemm_proj<2><<<512, 256, 0, stream>>>(v, wv, bv, Vt);
  attn_kernel<<<1024, 256, 0, stream>>>(Qh, Kh, Vt, Xa);
  gemm_proj<3><<<512, 256, 0, stream>>>(Xa, wo, bo, (float*)d_out);
}

// Round 7
// 155.708 us; speedup vs baseline: 2.5107x; 1.1218x over previous
//
#include <hip/hip_runtime.h>

#define DM 512
#define NH 8
#define DK 64
#define SEQ 4096

typedef short bf16x8 __attribute__((ext_vector_type(8)));
typedef float f32x4 __attribute__((ext_vector_type(4)));
typedef unsigned short u16;
typedef u16 u16x8 __attribute__((ext_vector_type(8)));
typedef u16 u16x4 __attribute__((ext_vector_type(4)));
typedef unsigned int u32;
typedef u32 u32x2 __attribute__((ext_vector_type(2)));

__device__ __forceinline__ u16 f2bf(float f) {
  union { float f; unsigned u; } v; v.f = f;
  unsigned r = v.u + 0x7fffu + ((v.u >> 16) & 1u);
  return (u16)(r >> 16);
}

__device__ __forceinline__ u32 cvtpk(float a, float b) {
  u32 r; asm("v_cvt_pk_bf16_f32 %0, %1, %2" : "=v"(r) : "v"(a), "v"(b)); return r;
}

__device__ __forceinline__ float fexp2(float x) {
  float r; asm("v_exp_f32 %0, %1" : "=v"(r) : "v"(x)); return r;
}

__device__ __forceinline__ float fmax3(float a, float b, float c) {
  return fmaxf(fmaxf(a, b), c);  // fuses to v_max3_f32
}

// NT GEMM: C[m][e] = sum_d X[m][d]*W[e][d] + bias[e]; M=8192, N=K=512.
// 64x128 tiles, grid 512 (2 blocks/CU). Reg-prefetch split staging (T14).
// MODE 0: fp32 -> bf16 Qh[b][h][s][dk] * (0.125*log2(e))
// MODE 1: fp32 -> bf16 Kh
// MODE 2: fp32 -> bf16 Vt[b][h][dk][s]  (transposed)
// MODE 3: bf16 -> fp32 [b][s][e]
template<int MODE>
__global__ __launch_bounds__(256, 2)
void gemm_proj(const void* __restrict__ Xv, const float* __restrict__ W,
               const float* __restrict__ bias, void* __restrict__ Outv)
{
  __shared__ alignas(16) u16 Alds[64][72];
  __shared__ alignas(16) u16 Blds[128][72];
  const int t = threadIdx.x;
  const int bx = blockIdx.x & 127;  // m tile (128 of them, 64 rows)
  const int by = blockIdx.x >> 7;   // n tile (4, 128 cols)
  const int m0 = bx << 6, n0 = by << 7;
  const int lane = t & 63, w = t >> 6;
  const int lr = lane & 15, lg = lane >> 4;
  const int wr = w >> 1, wc = w & 1;

  f32x4 acc[2][4];
  #pragma unroll
  for (int i = 0; i < 2; ++i)
    #pragma unroll
    for (int j = 0; j < 4; ++j) acc[i][j] = (f32x4){0.f, 0.f, 0.f, 0.f};

  float4 xa[4]; u16x8 xa3[2]; float4 wb[8];

  auto loadX = [&](int k0) {
    if (MODE < 3) {
      const float* X = (const float*)Xv;
      #pragma unroll
      for (int i = 0; i < 4; ++i) {
        int f = (i << 8) + t;
        xa[i] = *(const float4*)(X + (size_t)(m0 + (f >> 4)) * 512 + k0 + ((f & 15) << 2));
      }
    } else {
      const u16* X = (const u16*)Xv;
      #pragma unroll
      for (int i = 0; i < 2; ++i) {
        int f = (i << 8) + t;
        xa3[i] = *(const u16x8*)(X + (size_t)(m0 + (f >> 3)) * 512 + k0 + ((f & 7) << 3));
      }
    }
    #pragma unroll
    for (int i = 0; i < 8; ++i) {
      int f = (i << 8) + t;
      wb[i] = *(const float4*)(W + (size_t)(n0 + (f >> 4)) * 512 + k0 + ((f & 15) << 2));
    }
  };

  loadX(0);
  for (int k0 = 0; k0 < 512; k0 += 64) {
    __syncthreads();
    if (MODE < 3) {
      #pragma unroll
      for (int i = 0; i < 4; ++i) {
        int f = (i << 8) + t;
        u16x4 p = { f2bf(xa[i].x), f2bf(xa[i].y), f2bf(xa[i].z), f2bf(xa[i].w) };
        *(u16x4*)&Alds[f >> 4][(f & 15) << 2] = p;
      }
    } else {
      #pragma unroll
      for (int i = 0; i < 2; ++i) {
        int f = (i << 8) + t;
        *(u16x8*)&Alds[f >> 3][(f & 7) << 3] = xa3[i];
      }
    }
    #pragma unroll
    for (int i = 0; i < 8; ++i) {
      int f = (i << 8) + t;
      u16x4 p = { f2bf(wb[i].x), f2bf(wb[i].y), f2bf(wb[i].z), f2bf(wb[i].w) };
      *(u16x4*)&Blds[f >> 4][(f & 15) << 2] = p;
    }
    __syncthreads();
    if (k0 + 64 < 512) loadX(k0 + 64);  // prefetch hides under MFMA

    #pragma unroll
    for (int kk = 0; kk < 2; ++kk) {
      bf16x8 af[2], bfr[4];
      #pragma unroll
      for (int mi = 0; mi < 2; ++mi)
        af[mi] = *(const bf16x8*)&Alds[(wr << 5) + (mi << 4) + lr][(kk << 5) + (lg << 3)];
      #pragma unroll
      for (int ni = 0; ni < 4; ++ni)
        bfr[ni] = *(const bf16x8*)&Blds[(wc << 6) + (ni << 4) + lr][(kk << 5) + (lg << 3)];
      #pragma unroll
      for (int mi = 0; mi < 2; ++mi)
        #pragma unroll
        for (int ni = 0; ni < 4; ++ni)
          acc[mi][ni] = __builtin_amdgcn_mfma_f32_16x16x32_bf16(af[mi], bfr[ni], acc[mi][ni], 0, 0, 0);
    }
  }

  #pragma unroll
  for (int mi = 0; mi < 2; ++mi) {
    #pragma unroll
    for (int ni = 0; ni < 4; ++ni) {
      const int e = n0 + (wc << 6) + (ni << 4) + lr;
      const int m = m0 + (wr << 5) + (mi << 4) + (lg << 2);
      const float bb = bias[e];
      if (MODE == 0 || MODE == 1) {
        u16* O = (u16*)Outv;
        const int b = m >> 12, s = m & 4095, h = e >> 6, dk = e & 63;
        size_t base = ((size_t)((b << 3) + h) * SEQ + s) * DK + dk;
        #pragma unroll
        for (int r = 0; r < 4; ++r) {
          float val = acc[mi][ni][r] + bb;
          if (MODE == 0) val *= 0.18033688f;  // 0.125 * log2(e)
          O[base + (size_t)r * DK] = f2bf(val);
        }
      } else if (MODE == 2) {
        u16* O = (u16*)Outv;
        const int b = m >> 12, s = m & 4095, h = e >> 6, dk = e & 63;
        size_t base = ((size_t)((b << 3) + h) * DK + dk) * SEQ + s;
        u16x4 p = { f2bf(acc[mi][ni][0] + bb), f2bf(acc[mi][ni][1] + bb),
                    f2bf(acc[mi][ni][2] + bb), f2bf(acc[mi][ni][3] + bb) };
        *(u16x4*)(O + base) = p;
      } else {
        float* O = (float*)Outv;
        size_t base = (size_t)m * 512 + e;
        #pragma unroll
        for (int r = 0; r < 4; ++r) O[base + (size_t)r * 512] = acc[mi][ni][r] + bb;
      }
    }
  }
}

// Flash attention: round-4 validated structure (128-row q-tile, 4 waves x 32 rows,
// 2 blocks/CU, max-tracked defer-max softmax). Deltas vs round 4:
//   (1) l via ones-row MFMA (replaces psum adds + 2 serial shfls)
//   (2) max3-shaped row-max tree
__global__ __launch_bounds__(256, 2)
void attn_kernel(const u16* __restrict__ Qh, const u16* __restrict__ Kh,
                 const u16* __restrict__ Vt, u16* __restrict__ Xa)
{
  // [0..4095] K [64 kv][64 d] swizzled; [4096..8191] V [64 d][64 kv] swizzled
  // [8192..12799] P: 4 waves x 16 x 72 (padded)
  __shared__ alignas(16) u16 smem[12800];

  const int t = threadIdx.x;
  const int lane = t & 63, w = t >> 6;
  const int lr = lane & 15, lg = lane >> 4;
  const int ob = ((blockIdx.x & 7) << 6) + (blockIdx.x >> 3);  // XCD-bijective (512%8==0)
  const int qb = ob & 31, bh = ob >> 5;
  const size_t qkbase = (size_t)bh * SEQ * DK;
  const size_t vbase  = (size_t)bh * DK * SEQ;
  u16* Pw = smem + 8192 + w * 1152;

  // Q fragments (B-operand): q-row = w*32 + mi*16 + lr, k-slice = kk*32+lg*8
  bf16x8 qf[2][2];
  #pragma unroll
  for (int mi = 0; mi < 2; ++mi)
    #pragma unroll
    for (int kk = 0; kk < 2; ++kk) {
      int qrow = (qb << 7) + (w << 5) + (mi << 4) + lr;
      qf[mi][kk] = *(const bf16x8*)(Qh + qkbase + (size_t)qrow * DK + (kk << 5) + (lg << 3));
    }

  // ones A-fragment: row 0 (lr==0 lanes) = 1.0 bf16 -> D row 0 = column sums of B
  bf16x8 onesf;
  {
    u16 one = (lr == 0) ? (u16)0x3F80 : (u16)0;
    #pragma unroll
    for (int j = 0; j < 8; ++j) onesf[j] = (short)one;
  }

  float mrun[2] = {-3e38f, -3e38f};
  f32x4 o[2][4], osum[2];
  #pragma unroll
  for (int mi = 0; mi < 2; ++mi) {
    #pragma unroll
    for (int dt = 0; dt < 4; ++dt) o[mi][dt] = (f32x4){0.f, 0.f, 0.f, 0.f};
    osum[mi] = (f32x4){0.f, 0.f, 0.f, 0.f};
  }

  // staging: 512 granules of 16B per 64x64 tile, 2 per thread (round-4 layout)
  const u16* Kg = Kh + qkbase;
  const u16* Vg = Vt + vbase;
  const int r0 = t >> 3, c0 = t & 7;
  const int r1 = r0 + 32, c1 = c0;
  const int wk0 = r0 * 64 + ((c0 ^ (r0 & 7)) << 3);  // swizzled LDS (u16 units)
  const int wk1 = r1 * 64 + ((c1 ^ (r1 & 7)) << 3);

  u16x8 kr0, kr1, vr0, vr1;
  kr0 = *(const u16x8*)(Kg + (size_t)r0 * 64 + (c0 << 3));
  kr1 = *(const u16x8*)(Kg + (size_t)r1 * 64 + (c1 << 3));
  vr0 = *(const u16x8*)(Vg + (size_t)r0 * SEQ + (c0 << 3));
  vr1 = *(const u16x8*)(Vg + (size_t)r1 * SEQ + (c1 << 3));

  for (int it = 0; it < SEQ / 64; ++it) {
    __syncthreads();  // all waves done reading previous K/V
    *(u16x8*)&smem[wk0]        = kr0;
    *(u16x8*)&smem[wk1]        = kr1;
    *(u16x8*)&smem[4096 + wk0] = vr0;
    *(u16x8*)&smem[4096 + wk1] = vr1;
    __syncthreads();
    if (it + 1 < SEQ / 64) {  // prefetch next tile; hidden under compute
      const int kv0n = (it + 1) << 6;
      kr0 = *(const u16x8*)(Kg + (size_t)(kv0n + r0) * 64 + (c0 << 3));
      kr1 = *(const u16x8*)(Kg + (size_t)(kv0n + r1) * 64 + (c1 << 3));
      vr0 = *(const u16x8*)(Vg + (size_t)r0 * SEQ + kv0n + (c0 << 3));
      vr1 = *(const u16x8*)(Vg + (size_t)r1 * SEQ + kv0n + (c1 << 3));
    }

    // hoist K/V fragments (swizzled, conflict-free)
    bf16x8 kf[4][2], vf[4][2];
    #pragma unroll
    for (int nt = 0; nt < 4; ++nt)
      #pragma unroll
      for (int kk = 0; kk < 2; ++kk) {
        const int off = ((nt << 4) + lr) * 64 + ((((kk << 2) + lg) ^ (lr & 7)) << 3);
        kf[nt][kk] = *(const bf16x8*)&smem[off];
        vf[nt][kk] = *(const bf16x8*)&smem[4096 + off];
      }

    #pragma unroll
    for (int mi = 0; mi < 2; ++mi) {
      // S^T = K * Q^T : lane holds q = lr, kv = nt*16 + lg*4 + r  (exp2 domain)
      f32x4 s[4];
      #pragma unroll
      for (int nt = 0; nt < 4; ++nt) s[nt] = (f32x4){0.f, 0.f, 0.f, 0.f};
      #pragma unroll
      for (int kk = 0; kk < 2; ++kk)
        #pragma unroll
        for (int nt = 0; nt < 4; ++nt)
          s[nt] = __builtin_amdgcn_mfma_f32_16x16x32_bf16(kf[nt][kk], qf[mi][kk], s[nt], 0, 0, 0);

      // row max over 16 in-register values: 8x v_max3 + 2 cross-lane hops
      float m0 = fmax3(s[0][0], s[0][1], s[0][2]);
      float m1 = fmax3(s[0][3], s[1][0], s[1][1]);
      float m2 = fmax3(s[1][2], s[1][3], s[2][0]);
      float m3 = fmax3(s[2][1], s[2][2], s[2][3]);
      float m4 = fmax3(s[3][0], s[3][1], s[3][2]);
      float tmax = fmaxf(fmax3(m0, m1, m2), fmax3(m3, m4, s[3][3]));
      tmax = fmaxf(tmax, __shfl_xor(tmax, 16));
      tmax = fmaxf(tmax, __shfl_xor(tmax, 32));

      // defer-max: rescale only when some row's max grew past THR=8 (P <= 2^8)
      if (!__all(tmax <= mrun[mi] + 8.f)) {
        float mnew = fmaxf(mrun[mi], tmax);
        float scl = fexp2(mrun[mi] - mnew);
        mrun[mi] = mnew;
        osum[mi][0] *= scl;  // l lives in D-row 0
        #pragma unroll
        for (int dt = 0; dt < 4; ++dt) o[mi][dt] *= scl;
      }
      const float mm = mrun[mi];

      #pragma unroll
      for (int nt = 0; nt < 4; ++nt) {
        float e0 = fexp2(s[nt][0] - mm), e1 = fexp2(s[nt][1] - mm);
        float e2 = fexp2(s[nt][2] - mm), e3 = fexp2(s[nt][3] - mm);
        u32x2 pk2 = { cvtpk(e0, e1), cvtpk(e2, e3) };
        *(u32x2*)((char*)Pw + lr * 144 + (nt << 5) + (lg << 3)) = pk2;
      }

      // O^T += V * P^T ; l(row 0 of D) += ones * P^T  -- same pf, consistent
      #pragma unroll
      for (int kk = 0; kk < 2; ++kk) {
        bf16x8 pf = *(const bf16x8*)&Pw[lr * 72 + (kk << 5) + (lg << 3)];
        #pragma unroll
        for (int dt = 0; dt < 4; ++dt)
          o[mi][dt] = __builtin_amdgcn_mfma_f32_16x16x32_bf16(vf[dt][kk], pf, o[mi][dt], 0, 0, 0);
        osum[mi] = __builtin_amdgcn_mfma_f32_16x16x32_bf16(onesf, pf, osum[mi], 0, 0, 0);
      }
    }
  }
  __syncthreads();  // all waves done with K/V/P before smem reuse

  // epilogue: l(q) = osum[mi][0] on lane q (lg==0); broadcast, normalize, store
  #pragma unroll
  for (int mi = 0; mi < 2; ++mi) {
    float lsum = __shfl(osum[mi][0], lr);
    float inv = 1.f / lsum;
    #pragma unroll
    for (int dt = 0; dt < 4; ++dt) {
      u16x4 v4 = { f2bf(o[mi][dt][0] * inv), f2bf(o[mi][dt][1] * inv),
                   f2bf(o[mi][dt][2] * inv), f2bf(o[mi][dt][3] * inv) };
      int row = (w << 5) + (mi << 4) + lr;
      *(u16x4*)&smem[row * 72 + (dt << 4) + (lg << 2)] = v4;
    }
  }
  __syncthreads();
  {
    const int b = bh >> 3, h = bh & 7;
    #pragma unroll
    for (int i = 0; i < 4; ++i) {
      int f = (i << 8) + t;
      int row = f >> 3, c8 = (f & 7) << 3;
      u16x8 val = *(const u16x8*)&smem[row * 72 + c8];
      *(u16x8*)(Xa + ((size_t)b * SEQ + (qb << 7) + row) * DM + (h << 6) + c8) = val;
    }
  }
}

extern "C" void kernel_launch(void* const* d_in, const int* in_sizes, int n_in,
                              void* d_out, int out_size, void* d_ws, size_t ws_size,
                              hipStream_t stream)
{
  const float* q  = (const float*)d_in[0];
  const float* k  = (const float*)d_in[1];
  const float* v  = (const float*)d_in[2];
  const float* wq = (const float*)d_in[3];
  const float* bq = (const float*)d_in[4];
  const float* wk = (const float*)d_in[5];
  const float* bk = (const float*)d_in[6];
  const float* wv = (const float*)d_in[7];
  const float* bv = (const float*)d_in[8];
  const float* wo = (const float*)d_in[9];
  const float* bo = (const float*)d_in[10];

  const size_t HS = (size_t)2 * NH * SEQ * DK;
  u16* Qh = (u16*)d_ws;
  u16* Kh = Qh + HS;
  u16* Vt = Kh + HS;
  u16* Xa = Vt + HS;

  gemm_proj<0><<<512, 256, 0, stream>>>(q, wq, bq, Qh);
  gemm_proj<1><<<512, 256, 0, stream>>>(k, wk, bk, Kh);
  gemm_proj<2><<<512, 256, 0, stream>>>(v, wv, bv, Vt);
  attn_kernel<<<512, 256, 0, stream>>>(Qh, Kh, Vt, Xa);
  gemm_proj<3><<<512, 256, 0, stream>>>(Xa, wo, bo, (float*)d_out);
}

// Round 8
// 150.009 us; speedup vs baseline: 2.6061x; 1.0380x over previous
//
#include <hip/hip_runtime.h>

#define DM 512
#define NH 8
#define DK 64
#define SEQ 4096

typedef short bf16x8 __attribute__((ext_vector_type(8)));
typedef float f32x4 __attribute__((ext_vector_type(4)));
typedef unsigned short u16;
typedef u16 u16x8 __attribute__((ext_vector_type(8)));
typedef u16 u16x4 __attribute__((ext_vector_type(4)));
typedef unsigned int u32;
typedef u32 u32x2 __attribute__((ext_vector_type(2)));

__device__ __forceinline__ u16 f2bf(float f) {
  union { float f; unsigned u; } v; v.f = f;
  unsigned r = v.u + 0x7fffu + ((v.u >> 16) & 1u);
  return (u16)(r >> 16);
}

__device__ __forceinline__ u32 cvtpk(float a, float b) {
  u32 r; asm("v_cvt_pk_bf16_f32 %0, %1, %2" : "=v"(r) : "v"(a), "v"(b)); return r;
}

__device__ __forceinline__ float fexp2(float x) {
  float r; asm("v_exp_f32 %0, %1" : "=v"(r) : "v"(x)); return r;
}

__device__ __forceinline__ float fmax3(float a, float b, float c) {
  return fmaxf(fmaxf(a, b), c);  // fuses to v_max3_f32
}

// ---- merged Q/K/V projection GEMM: grid 1536 = 3 modes x 512 blocks ----
// 64x128 tiles. mode 0: Qh * (0.125*log2 e); mode 1: Kh; mode 2: Vt (transposed).
__global__ __launch_bounds__(256, 2)
void gemm_qkv(const float* __restrict__ qx, const float* __restrict__ kx,
              const float* __restrict__ vx,
              const float* __restrict__ wq, const float* __restrict__ bq,
              const float* __restrict__ wk, const float* __restrict__ bk,
              const float* __restrict__ wv, const float* __restrict__ bv,
              u16* __restrict__ Qh, u16* __restrict__ Kh, u16* __restrict__ Vt)
{
  __shared__ alignas(16) u16 Alds[64][72];
  __shared__ alignas(16) u16 Blds[128][72];
  const int mode = blockIdx.x >> 9;
  const int bid = blockIdx.x & 511;
  const float* X = (mode == 0) ? qx : (mode == 1) ? kx : vx;
  const float* W = (mode == 0) ? wq : (mode == 1) ? wk : wv;
  const float* Bs = (mode == 0) ? bq : (mode == 1) ? bk : bv;

  const int t = threadIdx.x;
  const int bx = bid & 127, by = bid >> 7;
  const int m0 = bx << 6, n0 = by << 7;
  const int lane = t & 63, w = t >> 6;
  const int lr = lane & 15, lg = lane >> 4;
  const int wr = w >> 1, wc = w & 1;

  f32x4 acc[2][4];
  #pragma unroll
  for (int i = 0; i < 2; ++i)
    #pragma unroll
    for (int j = 0; j < 4; ++j) acc[i][j] = (f32x4){0.f, 0.f, 0.f, 0.f};

  float4 xa[4]; float4 wb[8];
  auto loadX = [&](int k0) {
    #pragma unroll
    for (int i = 0; i < 4; ++i) {
      int f = (i << 8) + t;
      xa[i] = *(const float4*)(X + (size_t)(m0 + (f >> 4)) * 512 + k0 + ((f & 15) << 2));
    }
    #pragma unroll
    for (int i = 0; i < 8; ++i) {
      int f = (i << 8) + t;
      wb[i] = *(const float4*)(W + (size_t)(n0 + (f >> 4)) * 512 + k0 + ((f & 15) << 2));
    }
  };

  loadX(0);
  for (int k0 = 0; k0 < 512; k0 += 64) {
    __syncthreads();
    #pragma unroll
    for (int i = 0; i < 4; ++i) {
      int f = (i << 8) + t;
      u16x4 p = { f2bf(xa[i].x), f2bf(xa[i].y), f2bf(xa[i].z), f2bf(xa[i].w) };
      *(u16x4*)&Alds[f >> 4][(f & 15) << 2] = p;
    }
    #pragma unroll
    for (int i = 0; i < 8; ++i) {
      int f = (i << 8) + t;
      u16x4 p = { f2bf(wb[i].x), f2bf(wb[i].y), f2bf(wb[i].z), f2bf(wb[i].w) };
      *(u16x4*)&Blds[f >> 4][(f & 15) << 2] = p;
    }
    __syncthreads();
    if (k0 + 64 < 512) loadX(k0 + 64);

    #pragma unroll
    for (int kk = 0; kk < 2; ++kk) {
      bf16x8 af[2], bfr[4];
      #pragma unroll
      for (int mi = 0; mi < 2; ++mi)
        af[mi] = *(const bf16x8*)&Alds[(wr << 5) + (mi << 4) + lr][(kk << 5) + (lg << 3)];
      #pragma unroll
      for (int ni = 0; ni < 4; ++ni)
        bfr[ni] = *(const bf16x8*)&Blds[(wc << 6) + (ni << 4) + lr][(kk << 5) + (lg << 3)];
      #pragma unroll
      for (int mi = 0; mi < 2; ++mi)
        #pragma unroll
        for (int ni = 0; ni < 4; ++ni)
          acc[mi][ni] = __builtin_amdgcn_mfma_f32_16x16x32_bf16(af[mi], bfr[ni], acc[mi][ni], 0, 0, 0);
    }
  }

  const float sc = (mode == 0) ? 0.18033688f : 1.0f;  // 0.125*log2(e) for Q
  #pragma unroll
  for (int mi = 0; mi < 2; ++mi) {
    #pragma unroll
    for (int ni = 0; ni < 4; ++ni) {
      const int e = n0 + (wc << 6) + (ni << 4) + lr;
      const int m = m0 + (wr << 5) + (mi << 4) + (lg << 2);
      const float bb = Bs[e];
      const int b = m >> 12, s = m & 4095, h = e >> 6, dk = e & 63;
      if (mode != 2) {
        u16* O = (mode == 0) ? Qh : Kh;
        size_t base = ((size_t)((b << 3) + h) * SEQ + s) * DK + dk;
        #pragma unroll
        for (int r = 0; r < 4; ++r)
          O[base + (size_t)r * DK] = f2bf((acc[mi][ni][r] + bb) * sc);
      } else {
        size_t base = ((size_t)((b << 3) + h) * DK + dk) * SEQ + s;
        u16x4 p = { f2bf(acc[mi][ni][0] + bb), f2bf(acc[mi][ni][1] + bb),
                    f2bf(acc[mi][ni][2] + bb), f2bf(acc[mi][ni][3] + bb) };
        *(u16x4*)(Vt + base) = p;
      }
    }
  }
}

// ---- output projection (round-5 validated T14 GEMM, bf16 -> fp32) ----
__global__ __launch_bounds__(256, 2)
void gemm_out(const u16* __restrict__ Xa, const float* __restrict__ W,
              const float* __restrict__ bias, float* __restrict__ Out)
{
  __shared__ alignas(16) u16 Alds[64][72];
  __shared__ alignas(16) u16 Blds[128][72];
  const int t = threadIdx.x;
  const int bx = blockIdx.x & 127, by = blockIdx.x >> 7;
  const int m0 = bx << 6, n0 = by << 7;
  const int lane = t & 63, w = t >> 6;
  const int lr = lane & 15, lg = lane >> 4;
  const int wr = w >> 1, wc = w & 1;

  f32x4 acc[2][4];
  #pragma unroll
  for (int i = 0; i < 2; ++i)
    #pragma unroll
    for (int j = 0; j < 4; ++j) acc[i][j] = (f32x4){0.f, 0.f, 0.f, 0.f};

  u16x8 xa3[2]; float4 wb[8];
  auto loadX = [&](int k0) {
    #pragma unroll
    for (int i = 0; i < 2; ++i) {
      int f = (i << 8) + t;
      xa3[i] = *(const u16x8*)(Xa + (size_t)(m0 + (f >> 3)) * 512 + k0 + ((f & 7) << 3));
    }
    #pragma unroll
    for (int i = 0; i < 8; ++i) {
      int f = (i << 8) + t;
      wb[i] = *(const float4*)(W + (size_t)(n0 + (f >> 4)) * 512 + k0 + ((f & 15) << 2));
    }
  };

  loadX(0);
  for (int k0 = 0; k0 < 512; k0 += 64) {
    __syncthreads();
    #pragma unroll
    for (int i = 0; i < 2; ++i) {
      int f = (i << 8) + t;
      *(u16x8*)&Alds[f >> 3][(f & 7) << 3] = xa3[i];
    }
    #pragma unroll
    for (int i = 0; i < 8; ++i) {
      int f = (i << 8) + t;
      u16x4 p = { f2bf(wb[i].x), f2bf(wb[i].y), f2bf(wb[i].z), f2bf(wb[i].w) };
      *(u16x4*)&Blds[f >> 4][(f & 15) << 2] = p;
    }
    __syncthreads();
    if (k0 + 64 < 512) loadX(k0 + 64);

    #pragma unroll
    for (int kk = 0; kk < 2; ++kk) {
      bf16x8 af[2], bfr[4];
      #pragma unroll
      for (int mi = 0; mi < 2; ++mi)
        af[mi] = *(const bf16x8*)&Alds[(wr << 5) + (mi << 4) + lr][(kk << 5) + (lg << 3)];
      #pragma unroll
      for (int ni = 0; ni < 4; ++ni)
        bfr[ni] = *(const bf16x8*)&Blds[(wc << 6) + (ni << 4) + lr][(kk << 5) + (lg << 3)];
      #pragma unroll
      for (int mi = 0; mi < 2; ++mi)
        #pragma unroll
        for (int ni = 0; ni < 4; ++ni)
          acc[mi][ni] = __builtin_amdgcn_mfma_f32_16x16x32_bf16(af[mi], bfr[ni], acc[mi][ni], 0, 0, 0);
    }
  }

  #pragma unroll
  for (int mi = 0; mi < 2; ++mi) {
    #pragma unroll
    for (int ni = 0; ni < 4; ++ni) {
      const int e = n0 + (wc << 6) + (ni << 4) + lr;
      const int m = m0 + (wr << 5) + (mi << 4) + (lg << 2);
      const float bb = bias[e];
      size_t base = (size_t)m * 512 + e;
      #pragma unroll
      for (int r = 0; r < 4; ++r) Out[base + (size_t)r * 512] = acc[mi][ni][r] + bb;
    }
  }
}

// ---- Flash attention, KVBLK=128 (half the barriers), dual P regions,
//      setprio around MFMA clusters. Grid 512 = 16 bh x 32 q-tiles(128). ----
__global__ __launch_bounds__(256, 2)
void attn_kernel(const u16* __restrict__ Qh, const u16* __restrict__ Kh,
                 const u16* __restrict__ Vt, u16* __restrict__ Xa)
{
  // u16 units: K [0..8191] = [128 kv][64 d] swz(c^(r&7));
  //            V [8192..16383] = [64 d][128 kv] swz(c^(r&15));
  //            P [16384..] 4 waves x 2 x [16][136]
  __shared__ alignas(16) u16 smem[33792];

  const int t = threadIdx.x;
  const int lane = t & 63, w = t >> 6;
  const int lr = lane & 15, lg = lane >> 4;
  const int ob = ((blockIdx.x & 7) << 6) + (blockIdx.x >> 3);  // XCD-bijective
  const int qb = ob & 31, bh = ob >> 5;
  const size_t qkbase = (size_t)bh * SEQ * DK;
  const size_t vbase  = (size_t)bh * DK * SEQ;
  u16* P0 = smem + 16384 + w * 4352;
  u16* P1 = P0 + 2176;

  bf16x8 qf[2][2];
  #pragma unroll
  for (int mi = 0; mi < 2; ++mi)
    #pragma unroll
    for (int kk = 0; kk < 2; ++kk) {
      int qrow = (qb << 7) + (w << 5) + (mi << 4) + lr;
      qf[mi][kk] = *(const bf16x8*)(Qh + qkbase + (size_t)qrow * DK + (kk << 5) + (lg << 3));
    }

  bf16x8 onesf;
  {
    u16 one = (lr == 0) ? (u16)0x3F80 : (u16)0;
    #pragma unroll
    for (int j = 0; j < 8; ++j) onesf[j] = (short)one;
  }

  float mrun[2] = {-3e38f, -3e38f};
  f32x4 o[2][4], osum[2];
  #pragma unroll
  for (int mi = 0; mi < 2; ++mi) {
    #pragma unroll
    for (int dt = 0; dt < 4; ++dt) o[mi][dt] = (f32x4){0.f, 0.f, 0.f, 0.f};
    osum[mi] = (f32x4){0.f, 0.f, 0.f, 0.f};
  }

  // staging: K tile 128x64 = 1024 granules(16B); V tile 64x128 = 1024; 4+4/thread
  const u16* Kg = Kh + qkbase;
  const u16* Vg = Vt + vbase;
  int kro[4], kco[4], kdst[4], vro[4], vco[4], vdst[4];
  #pragma unroll
  for (int i = 0; i < 4; ++i) {
    int G = t + (i << 8);
    int kr = G >> 3, kc = G & 7;
    int vr = G >> 4, vc = G & 15;
    kro[i] = kr; kco[i] = kc << 3;
    vro[i] = vr; vco[i] = vc << 3;
    kdst[i] = kr * 64 + ((kc ^ (kr & 7)) << 3);
    vdst[i] = 8192 + vr * 128 + ((vc ^ (vr & 15)) << 3);
  }

  u16x8 kpr[4], vpr[4];
  #pragma unroll
  for (int i = 0; i < 4; ++i) {
    kpr[i] = *(const u16x8*)(Kg + (size_t)kro[i] * 64 + kco[i]);
    vpr[i] = *(const u16x8*)(Vg + (size_t)vro[i] * SEQ + vco[i]);
  }

  // softmax+P-store for one mi (inlined twice)
  auto softmax_store = [&](f32x4* s, float& mr, f32x4* oo, f32x4& os, u16* P) {
    float tm[8];
    #pragma unroll
    for (int nt = 0; nt < 8; ++nt)
      tm[nt] = fmaxf(fmax3(s[nt][0], s[nt][1], s[nt][2]), s[nt][3]);
    float tmax = fmax3(fmax3(tm[0], tm[1], tm[2]), fmax3(tm[3], tm[4], tm[5]),
                       fmaxf(tm[6], tm[7]));
    tmax = fmaxf(tmax, __shfl_xor(tmax, 16));
    tmax = fmaxf(tmax, __shfl_xor(tmax, 32));
    if (!__all(tmax <= mr + 8.f)) {   // defer-max THR=8 (P <= 2^8)
      float mnew = fmaxf(mr, tmax);
      float scl = fexp2(mr - mnew);
      mr = mnew;
      os[0] *= scl;
      #pragma unroll
      for (int dt = 0; dt < 4; ++dt) oo[dt] *= scl;
    }
    const float mm = mr;
    #pragma unroll
    for (int nt = 0; nt < 8; ++nt) {
      float e0 = fexp2(s[nt][0] - mm), e1 = fexp2(s[nt][1] - mm);
      float e2 = fexp2(s[nt][2] - mm), e3 = fexp2(s[nt][3] - mm);
      u32x2 pk2 = { cvtpk(e0, e1), cvtpk(e2, e3) };
      *(u32x2*)((char*)P + lr * 272 + (nt << 5) + (lg << 3)) = pk2;
    }
  };

  for (int it = 0; it < SEQ / 128; ++it) {
    __syncthreads();  // all waves done reading previous K/V
    #pragma unroll
    for (int i = 0; i < 4; ++i) {
      *(u16x8*)&smem[kdst[i]] = kpr[i];
      *(u16x8*)&smem[vdst[i]] = vpr[i];
    }
    __syncthreads();
    if (it + 1 < SEQ / 128) {  // prefetch next tile; hidden under compute
      const int kv0n = (it + 1) << 7;
      #pragma unroll
      for (int i = 0; i < 4; ++i) {
        kpr[i] = *(const u16x8*)(Kg + (size_t)(kv0n + kro[i]) * 64 + kco[i]);
        vpr[i] = *(const u16x8*)(Vg + (size_t)vro[i] * SEQ + kv0n + vco[i]);
      }
    }

    // QK^T both mi: lane holds q = lr, kv = nt*16 + lg*4 + r (exp2 domain)
    f32x4 s0[8], s1[8];
    #pragma unroll
    for (int nt = 0; nt < 8; ++nt) {
      s0[nt] = (f32x4){0.f, 0.f, 0.f, 0.f};
      s1[nt] = (f32x4){0.f, 0.f, 0.f, 0.f};
    }
    #pragma unroll
    for (int nt = 0; nt < 8; ++nt) {
      const int row = ((nt << 4) + lr) * 64;
      bf16x8 kf0 = *(const bf16x8*)&smem[row + ((lg ^ (lr & 7)) << 3)];
      bf16x8 kf1 = *(const bf16x8*)&smem[row + (((4 + lg) ^ (lr & 7)) << 3)];
      __builtin_amdgcn_s_setprio(1);
      s0[nt] = __builtin_amdgcn_mfma_f32_16x16x32_bf16(kf0, qf[0][0], s0[nt], 0, 0, 0);
      s0[nt] = __builtin_amdgcn_mfma_f32_16x16x32_bf16(kf1, qf[0][1], s0[nt], 0, 0, 0);
      s1[nt] = __builtin_amdgcn_mfma_f32_16x16x32_bf16(kf0, qf[1][0], s1[nt], 0, 0, 0);
      s1[nt] = __builtin_amdgcn_mfma_f32_16x16x32_bf16(kf1, qf[1][1], s1[nt], 0, 0, 0);
      __builtin_amdgcn_s_setprio(0);
    }

    softmax_store(s0, mrun[0], o[0], osum[0], P0);
    softmax_store(s1, mrun[1], o[1], osum[1], P1);

    // O^T += V * P^T ; l += ones * P^T  (vf read once per kk, shared by both mi)
    #pragma unroll
    for (int kk = 0; kk < 4; ++kk) {
      bf16x8 vf[4];
      #pragma unroll
      for (int dt = 0; dt < 4; ++dt)
        vf[dt] = *(const bf16x8*)&smem[8192 + ((dt << 4) + lr) * 128 +
                                       ((((kk << 2) + lg) ^ lr) << 3)];
      bf16x8 pf0 = *(const bf16x8*)&P0[lr * 136 + (kk << 5) + (lg << 3)];
      bf16x8 pf1 = *(const bf16x8*)&P1[lr * 136 + (kk << 5) + (lg << 3)];
      __builtin_amdgcn_s_setprio(1);
      #pragma unroll
      for (int dt = 0; dt < 4; ++dt)
        o[0][dt] = __builtin_amdgcn_mfma_f32_16x16x32_bf16(vf[dt], pf0, o[0][dt], 0, 0, 0);
      osum[0] = __builtin_amdgcn_mfma_f32_16x16x32_bf16(onesf, pf0, osum[0], 0, 0, 0);
      #pragma unroll
      for (int dt = 0; dt < 4; ++dt)
        o[1][dt] = __builtin_amdgcn_mfma_f32_16x16x32_bf16(vf[dt], pf1, o[1][dt], 0, 0, 0);
      osum[1] = __builtin_amdgcn_mfma_f32_16x16x32_bf16(onesf, pf1, osum[1], 0, 0, 0);
      __builtin_amdgcn_s_setprio(0);
    }
  }
  __syncthreads();  // all waves done with K/V/P before smem reuse

  // epilogue: l(q) = osum[mi][0] on lane q; broadcast, normalize, stage, store
  #pragma unroll
  for (int mi = 0; mi < 2; ++mi) {
    float lsum = __shfl(osum[mi][0], lr);
    float inv = 1.f / lsum;
    #pragma unroll
    for (int dt = 0; dt < 4; ++dt) {
      u16x4 v4 = { f2bf(o[mi][dt][0] * inv), f2bf(o[mi][dt][1] * inv),
                   f2bf(o[mi][dt][2] * inv), f2bf(o[mi][dt][3] * inv) };
      int row = (w << 5) + (mi << 4) + lr;
      *(u16x4*)&smem[row * 72 + (dt << 4) + (lg << 2)] = v4;
    }
  }
  __syncthreads();
  {
    const int b = bh >> 3, h = bh & 7;
    #pragma unroll
    for (int i = 0; i < 4; ++i) {
      int f = (i << 8) + t;
      int row = f >> 3, c8 = (f & 7) << 3;
      u16x8 val = *(const u16x8*)&smem[row * 72 + c8];
      *(u16x8*)(Xa + ((size_t)b * SEQ + (qb << 7) + row) * DM + (h << 6) + c8) = val;
    }
  }
}

extern "C" void kernel_launch(void* const* d_in, const int* in_sizes, int n_in,
                              void* d_out, int out_size, void* d_ws, size_t ws_size,
                              hipStream_t stream)
{
  const float* q  = (const float*)d_in[0];
  const float* k  = (const float*)d_in[1];
  const float* v  = (const float*)d_in[2];
  const float* wq = (const float*)d_in[3];
  const float* bq = (const float*)d_in[4];
  const float* wk = (const float*)d_in[5];
  const float* bk = (const float*)d_in[6];
  const float* wv = (const float*)d_in[7];
  const float* bv = (const float*)d_in[8];
  const float* wo = (const float*)d_in[9];
  const float* bo = (const float*)d_in[10];

  const size_t HS = (size_t)2 * NH * SEQ * DK;
  u16* Qh = (u16*)d_ws;
  u16* Kh = Qh + HS;
  u16* Vt = Kh + HS;
  u16* Xa = Vt + HS;

  gemm_qkv<<<1536, 256, 0, stream>>>(q, k, v, wq, bq, wk, bk, wv, bv, Qh, Kh, Vt);
  attn_kernel<<<512, 256, 0, stream>>>(Qh, Kh, Vt, Xa);
  gemm_out<<<512, 256, 0, stream>>>(Xa, wo, bo, (float*)d_out);
}